// Round 5
// baseline (1876.807 us; speedup 1.0000x reference)
//
#include <hip/hip_runtime.h>
#include <hip/hip_bf16.h>
#include <cstdio>
#include <math.h>

// GraphAttention forward, MI355X/gfx950.  Inputs/outputs FLOAT32.
// out0: bf16 MFMA path (PASSES at 2e-2).
// out1: EXACT numpy-fp32 emulation (established R4-R6: fp64 is not enough; the
// binary threshold decisions require bit-identical fp32):
//   - einsum sums (feats over f, logits over k, temp over j): SSE 4-lane 1-acc
//     dot, lane = idx%4, hsum ((a0+a1)+(a2+a3))
//   - np.sum reductions: numpy pairwise_sum, AVX512 base case
//   - exp/sigmoid: correctly-rounded fp32 via fp64 exp
//   - all fp32 ops correctly rounded, NO FMA contraction
//
// R11 (this round): feats32_emu4 at 268us, VALU busy-time ~126us < 218us scalar
// floor -> compiler already part-packs into v_pk_*_f32 but pays pair-assembly
// movs + stalls (2 barriers/chunk, shallow weight lookahead). v5: (a) weights
// repacked PAIR-ADJACENT [h][kg][f/2][q][2] so packed ops need no shuffles;
// (b) explicit float2 packed arithmetic under `clang fp contract(off)`
// (elementwise IEEE-RN = __fmul_rn/__fadd_rn bits; per-accumulator chain order
// f-ascending preserved; only independent chains reordered); (c) X LDS
// double-buffered (FCH=64), next-chunk global loads issued before compute,
// 1 barrier/chunk.

typedef __attribute__((ext_vector_type(8))) short   s16x8;
typedef __attribute__((ext_vector_type(8))) __bf16  bf16x8;
typedef __attribute__((ext_vector_type(4))) float   fx4;
typedef __attribute__((ext_vector_type(2))) float   fx2;

#define FADD __fadd_rn
#define FMUL __fmul_rn
#define FSUB __fsub_rn
#define FDIV __fdiv_rn
#define MASKC (-9999998976.0f)   // fl32(-1e10)

__device__ __forceinline__ fx4 mfma_bf16_16x16x32(s16x8 a, s16x8 b, fx4 c) {
    return __builtin_amdgcn_mfma_f32_16x16x32_bf16(
        __builtin_bit_cast(bf16x8, a), __builtin_bit_cast(bf16x8, b), c, 0, 0, 0);
}
__device__ __forceinline__ unsigned short f2bf(float f) {
    unsigned int x = __builtin_bit_cast(unsigned int, f);
    unsigned int lsb = (x >> 16) & 1u;
    x += 0x7fffu + lsb;
    return (unsigned short)(x >> 16);
}
__device__ __forceinline__ unsigned int pack2(float a, float b) {
    return (unsigned int)f2bf(a) | ((unsigned int)f2bf(b) << 16);
}
__device__ __forceinline__ float expf_cr(float x) {   // correctly-rounded expf
    return (float)exp((double)x);
}

// numpy pairwise_sum base (n=128), AVX512 flavor.
__device__ float pw128(const float* a) {
    float c[16];
#pragma unroll
    for (int l = 0; l < 16; ++l) {
        float t0 = FADD(FADD(a[l], a[16 + l]), FADD(a[32 + l], a[48 + l]));
        float t1 = FADD(FADD(a[64 + l], a[80 + l]), FADD(a[96 + l], a[112 + l]));
        c[l] = FADD(t0, t1);
    }
    float d[8], e[4], f[2];
#pragma unroll
    for (int l = 0; l < 8; ++l) d[l] = FADD(c[l], c[l + 8]);
#pragma unroll
    for (int l = 0; l < 4; ++l) e[l] = FADD(d[l], d[l + 4]);
#pragma unroll
    for (int l = 0; l < 2; ++l) f[l] = FADD(e[l], e[l + 2]);
    return FADD(f[0], f[1]);
}

// ---------------------------------------------------------------- out0 support
__global__ __launch_bounds__(256) void repack_w(const float* __restrict__ kern,
                                                unsigned short* __restrict__ wkt) {
    int t = blockIdx.x * 256 + threadIdx.x;
    int n = t >> 9, f = t & 511;
    int h = n >> 6, k = n & 63;
    wkt[t] = f2bf(kern[(h * 512 + f) * 64 + k]);
}

// pair-adjacent fp32 repack: kern_r2[((((h*8+kg)*256+fp)*8+q)*2)+e] = kern[h][2*fp+e][kg*8+q]
__global__ __launch_bounds__(256) void repack_k32p(const float* __restrict__ kern,
                                                   float* __restrict__ kern_r2) {
    int t = blockIdx.x * 256 + threadIdx.x;      // 262,144
    int e  = t & 1;
    int q  = (t >> 1) & 7;
    int fp = (t >> 4) & 255;
    int kgh = t >> 12;                            // 0..63
    int kg = kgh & 7, h = kgh >> 3;
    int f = fp * 2 + e;
    kern_r2[t] = kern[(h * 512 + f) * 64 + kg * 8 + q];
}

#define BK 32
__global__ __launch_bounds__(256) void gemm_feats(const float* __restrict__ X,
                                                  const unsigned short* __restrict__ Wkt,
                                                  unsigned short* __restrict__ feats_bf) {
    __shared__ alignas(16) unsigned short As[128 * BK];
    __shared__ alignas(16) unsigned short Bs[128 * BK];
    const int tid = threadIdx.x;
    const int mb = blockIdx.x >> 2, nb = blockIdx.x & 3;
    const int m0 = mb * 128, n0 = nb * 128;
    const int w = tid >> 6, lane = tid & 63;
    const int mw = (w & 1) * 64, nw = (w >> 1) * 64;
    const int lr = lane & 15, lq = lane >> 4;
    const int srow = tid >> 2, scol = (tid & 3) * 8;

    fx4 acc[4][4] = {};
    for (int k0 = 0; k0 < 512; k0 += BK) {
        __syncthreads();
        {
            const float* xr0 = &X[(m0 + srow) * 512 + k0 + scol];
            const float* xr1 = &X[(m0 + srow + 64) * 512 + k0 + scol];
            float4 a0 = *(const float4*)xr0, a1 = *(const float4*)(xr0 + 4);
            float4 b0 = *(const float4*)xr1, b1 = *(const float4*)(xr1 + 4);
            uint4 p0 = { pack2(a0.x, a0.y), pack2(a0.z, a0.w), pack2(a1.x, a1.y), pack2(a1.z, a1.w) };
            uint4 p1 = { pack2(b0.x, b0.y), pack2(b0.z, b0.w), pack2(b1.x, b1.y), pack2(b1.z, b1.w) };
            *(uint4*)&As[srow * BK + scol]        = p0;
            *(uint4*)&As[(srow + 64) * BK + scol] = p1;
            *(uint4*)&Bs[srow * BK + scol]        = *(const uint4*)&Wkt[(n0 + srow) * 512 + k0 + scol];
            *(uint4*)&Bs[(srow + 64) * BK + scol] = *(const uint4*)&Wkt[(n0 + srow + 64) * 512 + k0 + scol];
        }
        __syncthreads();
        s16x8 a[4], bb[4];
#pragma unroll
        for (int i = 0; i < 4; ++i) a[i]  = *(const s16x8*)&As[(mw + i * 16 + lr) * BK + lq * 8];
#pragma unroll
        for (int i = 0; i < 4; ++i) bb[i] = *(const s16x8*)&Bs[(nw + i * 16 + lr) * BK + lq * 8];
#pragma unroll
        for (int i = 0; i < 4; ++i)
#pragma unroll
            for (int j = 0; j < 4; ++j)
                acc[i][j] = mfma_bf16_16x16x32(a[i], bb[j], acc[i][j]);
    }
#pragma unroll
    for (int i = 0; i < 4; ++i)
#pragma unroll
        for (int j = 0; j < 4; ++j) {
            int col  = n0 + nw + j * 16 + lr;
            int rowb = m0 + mw + i * 16 + lq * 4;
#pragma unroll
            for (int r = 0; r < 4; ++r)
                feats_bf[(rowb + r) * 512 + col] = f2bf(acc[i][j][r]);
        }
}

// ---------------------------------------------------------------- feats32 (np emu, v5)
// Packed-pair formulation. Per output (h,row,k): 4 SSE accumulator chains by
// f%4, pairs (a0,a1) and (a2,a3) kept as fx2. Chain order per accumulator is
// f-ascending exactly as numpy: a0: +x0w0,+x4w4,... (identical bits).
#define FCH2 64
#define XS2_STRIDE 68   // floats; 16B-aligned rows
__global__ __launch_bounds__(512) void feats32_emu5(const float* __restrict__ X,
                                                    const float* __restrict__ kern_r2,
                                                    float* __restrict__ feats32) {
#pragma clang fp contract(off)
    __shared__ alignas(16) float Xs[2][64 * XS2_STRIDE];   // 34,816 B
    const int tid = threadIdx.x;
    const int hg = blockIdx.x >> 9;          // 0..3  (grid = 4 * 512)
    const int rb = blockIdx.x & 511;         // 0..511
    const int h0 = hg * 2;
    const int lane = tid & 63;
    const int kg = __builtin_amdgcn_readfirstlane(tid >> 6);   // wave-uniform 0..7
    const int k0 = kg * 8;
    const int row0 = rb * 64;
    const int srow = tid >> 3, sseg = tid & 7;   // staging: 64 rows x 8 segs x 8 floats

    fx2 acc01[2][8];   // (a0,a1) per head per q
    fx2 acc23[2][8];   // (a2,a3)
#pragma unroll
    for (int hh = 0; hh < 2; ++hh)
#pragma unroll
        for (int q = 0; q < 8; ++q) {
            acc01[hh][q] = (fx2)(0.f);
            acc23[hh][q] = (fx2)(0.f);
        }

    // per-(h,kg) weight slices, 16KB each, contiguous, pair-adjacent
    const float* __restrict__ kp0 = &kern_r2[(((h0 + 0) * 8 + kg) * 256) * 16];
    const float* __restrict__ kp1 = &kern_r2[(((h0 + 1) * 8 + kg) * 256) * 16];

    // prologue: stage chunk 0
    float4 nx0, nx1;
    {
        const float* gp = &X[(row0 + srow) * 512 + sseg * 8];
        nx0 = *(const float4*)gp; nx1 = *(const float4*)(gp + 4);
        *(float4*)&Xs[0][srow * XS2_STRIDE + sseg * 8]     = nx0;
        *(float4*)&Xs[0][srow * XS2_STRIDE + sseg * 8 + 4] = nx1;
    }
    __syncthreads();

    for (int ch = 0; ch < 8; ++ch) {
        const int fc = ch * FCH2;
        const int cur = ch & 1;
        if (ch < 7) {   // issue next-chunk global loads (land during compute)
            const float* gp = &X[(row0 + srow) * 512 + fc + FCH2 + sseg * 8];
            nx0 = *(const float4*)gp; nx1 = *(const float4*)(gp + 4);
        }

        const float* __restrict__ xrow = &Xs[cur][lane * XS2_STRIDE];
#pragma unroll
        for (int fo = 0; fo < FCH2; fo += 8) {
            float4 xa = *(const float4*)&xrow[fo];
            float4 xb = *(const float4*)&xrow[fo + 4];
            fx2 x01; x01.x = xa.x; x01.y = xa.y;
            fx2 x23; x23.x = xa.z; x23.y = xa.w;
            fx2 x45; x45.x = xb.x; x45.y = xb.y;
            fx2 x67; x67.x = xb.z; x67.y = xb.w;
            const int fp0 = (fc + fo) >> 1;
#pragma unroll
            for (int hh = 0; hh < 2; ++hh) {
                const fx2* __restrict__ wv =
                    (const fx2*)((hh == 0 ? kp0 : kp1) + fp0 * 16);
                // wv[q]=(w[f][q],w[f+1][q]), wv[8+q]=(w[f+2][q],w[f+3][q]),
                // wv[16+q]=(w[f+4][q],w[f+5][q]), wv[24+q]=(w[f+6][q],w[f+7][q])
#pragma unroll
                for (int q = 0; q < 8; ++q) {
                    fx2 m0 = x01 * wv[q];
                    acc01[hh][q] = acc01[hh][q] + m0;
                    fx2 m1 = x45 * wv[16 + q];
                    acc01[hh][q] = acc01[hh][q] + m1;
                    fx2 m2 = x23 * wv[8 + q];
                    acc23[hh][q] = acc23[hh][q] + m2;
                    fx2 m3 = x67 * wv[24 + q];
                    acc23[hh][q] = acc23[hh][q] + m3;
                }
            }
        }

        if (ch < 7) {   // write next chunk into the other buffer
            *(float4*)&Xs[cur ^ 1][srow * XS2_STRIDE + sseg * 8]     = nx0;
            *(float4*)&Xs[cur ^ 1][srow * XS2_STRIDE + sseg * 8 + 4] = nx1;
        }
        __syncthreads();
    }

#pragma unroll
    for (int hh = 0; hh < 2; ++hh) {
        float* __restrict__ op = &feats32[((h0 + hh) * 32768 + row0 + lane) * 64 + k0];
        float4 o0, o1;
        o0.x = FADD(FADD(acc01[hh][0].x, acc01[hh][0].y), FADD(acc23[hh][0].x, acc23[hh][0].y));
        o0.y = FADD(FADD(acc01[hh][1].x, acc01[hh][1].y), FADD(acc23[hh][1].x, acc23[hh][1].y));
        o0.z = FADD(FADD(acc01[hh][2].x, acc01[hh][2].y), FADD(acc23[hh][2].x, acc23[hh][2].y));
        o0.w = FADD(FADD(acc01[hh][3].x, acc01[hh][3].y), FADD(acc23[hh][3].x, acc23[hh][3].y));
        o1.x = FADD(FADD(acc01[hh][4].x, acc01[hh][4].y), FADD(acc23[hh][4].x, acc23[hh][4].y));
        o1.y = FADD(FADD(acc01[hh][5].x, acc01[hh][5].y), FADD(acc23[hh][5].x, acc23[hh][5].y));
        o1.z = FADD(FADD(acc01[hh][6].x, acc01[hh][6].y), FADD(acc23[hh][6].x, acc23[hh][6].y));
        o1.w = FADD(FADD(acc01[hh][7].x, acc01[hh][7].y), FADD(acc23[hh][7].x, acc23[hh][7].y));
        *(float4*)&op[0] = o0;
        *(float4*)&op[4] = o1;
    }
}

// ---------------------------------------------------------------- logits (np emu)
__device__ float sse_dot64(const float* __restrict__ x, const float* __restrict__ y) {
    float a0 = 0.f, a1 = 0.f, a2 = 0.f, a3 = 0.f;
    for (int i = 0; i < 64; i += 8) {
        a0 = FADD(a0, FMUL(x[i + 0], y[i + 0]));
        a1 = FADD(a1, FMUL(x[i + 1], y[i + 1]));
        a2 = FADD(a2, FMUL(x[i + 2], y[i + 2]));
        a3 = FADD(a3, FMUL(x[i + 3], y[i + 3]));
        a0 = FADD(a0, FMUL(x[i + 4], y[i + 4]));
        a1 = FADD(a1, FMUL(x[i + 5], y[i + 5]));
        a2 = FADD(a2, FMUL(x[i + 6], y[i + 6]));
        a3 = FADD(a3, FMUL(x[i + 7], y[i + 7]));
    }
    return FADD(FADD(a0, a1), FADD(a2, a3));
}

__global__ __launch_bounds__(256) void logits_emu(const float* __restrict__ feats32,
                                                  const float* __restrict__ attn_s,
                                                  const float* __restrict__ attn_n,
                                                  float* __restrict__ a_s32,
                                                  float* __restrict__ a_n32) {
    int t = blockIdx.x * 256 + threadIdx.x;      // 262,144
    int row = t & 32767, h = t >> 15;
    const float* fr = &feats32[(h * 32768 + row) * 64];
    a_s32[h * 32768 + row] = sse_dot64(fr, &attn_s[h * 64]);
    a_n32[h * 32768 + row] = sse_dot64(fr, &attn_n[h * 64]);
}

// ---------------------------------------------------------------- attention (np-fp32 emu, v2)
#define VT_STRIDE 264
__global__ __launch_bounds__(256) void attn_emu(const float* __restrict__ A,
                                                const unsigned short* __restrict__ feats_bf,
                                                const float* __restrict__ a_s32,
                                                const float* __restrict__ a_n32,
                                                const float* __restrict__ biases,
                                                float* __restrict__ out0,
                                                float* __restrict__ view32) {
    __shared__ alignas(16) unsigned short Vt[64 * VT_STRIDE];   // 33792 B
    __shared__ alignas(16) unsigned int   Abits[64][8];         //  2048 B
    __shared__ alignas(16) float an_l[8][256];                  //  8192 B
    __shared__ alignas(16) float as_l[8][64];                   //  2048 B  = 46080 B

    const int tid = threadIdx.x;
    const int b = blockIdx.x >> 2;
    const int row0 = (blockIdx.x & 3) * 64;
    const int w = tid >> 6, lane = tid & 63;
    const int m = lane & 15, jq = lane >> 4;

    // stage adjacency as bitmask: 64 rows x 256 bits
    {
        int i = tid >> 2, sg = tid & 3;
        const float* ar = &A[(((b << 8) + row0 + i) << 8) + sg * 64];
        unsigned int w0 = 0, w1 = 0;
#pragma unroll
        for (int q = 0; q < 8; ++q) {
            float4 av = *(const float4*)&ar[q * 4];
            unsigned int m4 = (av.x != 0.f ? 1u : 0u) | (av.y != 0.f ? 2u : 0u) |
                              (av.z != 0.f ? 4u : 0u) | (av.w != 0.f ? 8u : 0u);
            w0 |= m4 << (q * 4);
        }
#pragma unroll
        for (int q = 8; q < 16; ++q) {
            float4 av = *(const float4*)&ar[q * 4];
            unsigned int m4 = (av.x != 0.f ? 1u : 0u) | (av.y != 0.f ? 2u : 0u) |
                              (av.z != 0.f ? 4u : 0u) | (av.w != 0.f ? 8u : 0u);
            w1 |= m4 << ((q - 8) * 4);
        }
        Abits[i][sg * 2]     = w0;
        Abits[i][sg * 2 + 1] = w1;
    }
    // stage logits (all heads)
    for (int idx = tid; idx < 2048; idx += 256) {
        int h = idx >> 8, j = idx & 255;
        an_l[h][j] = a_n32[h * 32768 + (b << 8) + j];
    }
    for (int idx = tid; idx < 512; idx += 256) {
        int h = idx >> 6, i = idx & 63;
        as_l[h][i] = a_s32[h * 32768 + (b << 8) + row0 + i];
    }
    __syncthreads();

    const int i_ln = w * 16 + m;
    const int myrow = row0 + i_ln;
    unsigned int abits[8];
#pragma unroll
    for (int u = 0; u < 8; ++u) abits[u] = Abits[i_ln][u];

    float view_acc[8][8] = {};

    for (int h = 0; h < 8; ++h) {
        __syncthreads();
        {   // stage V^T for this head: 16B global loads, scalar LDS writes
            int jb = w;
#pragma unroll
            for (int it = 0; it < 8; ++it) {
                int j  = jb * 64 + it * 8 + (lane >> 3);
                int kg = lane & 7;
                s16x8 v8 = *(const s16x8*)&feats_bf[(((b << 8) + j) << 9) + (h << 6) + kg * 8];
#pragma unroll
                for (int u = 0; u < 8; ++u)
                    Vt[(kg * 8 + u) * VT_STRIDE + j] = (unsigned short)v8[u];
            }
        }
        __syncthreads();

        const float asv = as_l[h][i_ln];

        // ---- logits once, tracking local max
        float ev[8][8];
        float Mloc = -3.4e38f;
#pragma unroll
        for (int kb = 0; kb < 8; ++kb) {
            int jbase = kb * 32 + jq * 8;
            float4 an0 = *(const float4*)&an_l[h][jbase];
            float4 an1 = *(const float4*)&an_l[h][jbase + 4];
            float anv[8] = { an0.x, an0.y, an0.z, an0.w, an1.x, an1.y, an1.z, an1.w };
            unsigned int mb = (abits[kb] >> (jq * 8)) & 0xffu;
#pragma unroll
            for (int t = 0; t < 8; ++t) {
                float lg = FADD(asv, anv[t]);
                float lr = lg > 0.f ? lg : FMUL(0.2f, lg);
                float v  = (mb & (1u << t)) ? lr : FADD(lr, MASKC);
                ev[kb][t] = v;
                Mloc = fmaxf(Mloc, v);
            }
        }
        // ---- M: order-free cross-lane max over the row's 4 lanes
        Mloc = fmaxf(Mloc, __shfl_xor(Mloc, 16, 64));
        Mloc = fmaxf(Mloc, __shfl_xor(Mloc, 32, 64));
        const float Mi = Mloc;

        // ---- exp ONCE
#pragma unroll
        for (int kb = 0; kb < 8; ++kb)
#pragma unroll
            for (int t = 0; t < 8; ++t)
                ev[kb][t] = expf_cr(FSUB(ev[kb][t], Mi));

        // ---- S: numpy pairwise tree via shuffles (exact; FADD commutative)
        float blkS[2];
#pragma unroll
        for (int blk = 0; blk < 2; ++blk) {
            float d[8];
#pragma unroll
            for (int t = 0; t < 8; ++t) {
                float s0 = FADD(ev[blk * 4 + 0][t], __shfl_xor(ev[blk * 4 + 0][t], 32, 64));
                float s1 = FADD(ev[blk * 4 + 1][t], __shfl_xor(ev[blk * 4 + 1][t], 32, 64));
                float s2 = FADD(ev[blk * 4 + 2][t], __shfl_xor(ev[blk * 4 + 2][t], 32, 64));
                float s3 = FADD(ev[blk * 4 + 3][t], __shfl_xor(ev[blk * 4 + 3][t], 32, 64));
                float cc = FADD(FADD(s0, s1), FADD(s2, s3));   // c[l]
                d[t] = FADD(cc, __shfl_xor(cc, 16, 64));       // d[l] = c[l]+c[l+8]
            }
            float e4[4], f2[2];
#pragma unroll
            for (int t = 0; t < 4; ++t) e4[t] = FADD(d[t], d[t + 4]);
            f2[0] = FADD(e4[0], e4[2]);
            f2[1] = FADD(e4[1], e4[3]);
            blkS[blk] = FADD(f2[0], f2[1]);
        }
        const float Si = FADD(blkS[0], blkS[1]);

        // ---- p, view accumulate, PV MFMA
        s16x8 pfrag[8];
#pragma unroll
        for (int kb = 0; kb < 8; ++kb) {
            s16x8 pf;
#pragma unroll
            for (int t = 0; t < 8; ++t) {
                float p = FDIV(ev[kb][t], Si);
                view_acc[kb][t] = FADD(view_acc[kb][t], FMUL(p, 0.125f));
                pf[t] = (short)f2bf(p);
            }
            pfrag[kb] = pf;
        }

        fx4 acc[4] = {};
#pragma unroll
        for (int kb = 0; kb < 8; ++kb) {
            int jo = kb * 32 + jq * 8;
#pragma unroll
            for (int nf = 0; nf < 4; ++nf) {
                s16x8 vf = *(const s16x8*)&Vt[(nf * 16 + m) * VT_STRIDE + jo];
                acc[nf] = mfma_bf16_16x16x32(pfrag[kb], vf, acc[nf]);
            }
        }
#pragma unroll
        for (int nf = 0; nf < 4; ++nf) {
            float bias = biases[h * 64 + nf * 16 + m];
#pragma unroll
            for (int r = 0; r < 4; ++r) {
                float val = acc[nf][r] + bias;
                val = val > 0.f ? val : 0.f;
                int gi = (b << 8) + row0 + w * 16 + jq * 4 + r;
                out0[gi * 512 + h * 64 + nf * 16 + m] = val;
            }
        }
    }

#pragma unroll
    for (int kb = 0; kb < 8; ++kb) {
        int base = (((b << 8) + myrow) << 8) + kb * 32 + jq * 8;
        float4 v0, v1;
        v0.x = view_acc[kb][0]; v0.y = view_acc[kb][1]; v0.z = view_acc[kb][2]; v0.w = view_acc[kb][3];
        v1.x = view_acc[kb][4]; v1.y = view_acc[kb][5]; v1.z = view_acc[kb][6]; v1.w = view_acc[kb][7];
        *(float4*)&view32[base]     = v0;
        *(float4*)&view32[base + 4] = v1;
    }
}

// ---------------------------------------------------------------- pool / temp / thresh
__global__ __launch_bounds__(256) void pool_emu(const float* __restrict__ view32,
                                                float* __restrict__ pooled) {
    int t = blockIdx.x * 256 + threadIdx.x;      // 2,097,152
    int j = t & 127, i = (t >> 7) & 127, b = t >> 14;
    const float* p = &view32[(b << 16) + (2 * i) * 256 + 2 * j];
    pooled[t] = fmaxf(fmaxf(p[0], p[1]), fmaxf(p[256], p[257]));
}

// temp[b,i,k] = SSE dot over j=0..127: pooled row (contig) x alpha[:,k] (stride 128)
__global__ __launch_bounds__(256) void temp_emu(const float* __restrict__ pooled,
                                                const float* __restrict__ alpha,
                                                float* __restrict__ temp) {
    int t = blockIdx.x * 256 + threadIdx.x;      // 2,097,152
    int k = t & 127, i = (t >> 7) & 127, b = t >> 14;
    const float* pr = &pooled[(b << 14) + i * 128];
    const float* ap = &alpha[k];                  // stride 128 over j
    float a0 = 0.f, a1 = 0.f, a2 = 0.f, a3 = 0.f;
    for (int j = 0; j < 128; j += 8) {
        a0 = FADD(a0, FMUL(pr[j + 0], ap[(j + 0) * 128]));
        a1 = FADD(a1, FMUL(pr[j + 1], ap[(j + 1) * 128]));
        a2 = FADD(a2, FMUL(pr[j + 2], ap[(j + 2) * 128]));
        a3 = FADD(a3, FMUL(pr[j + 3], ap[(j + 3) * 128]));
        a0 = FADD(a0, FMUL(pr[j + 4], ap[(j + 4) * 128]));
        a1 = FADD(a1, FMUL(pr[j + 5], ap[(j + 5) * 128]));
        a2 = FADD(a2, FMUL(pr[j + 6], ap[(j + 6) * 128]));
        a3 = FADD(a3, FMUL(pr[j + 7], ap[(j + 7) * 128]));
    }
    temp[t] = FADD(FADD(a0, a1), FADD(a2, a3));
}

// s[b] = numpy pairwise over 16384 (128 leaves of pw128, balanced binary tree)
__global__ __launch_bounds__(128) void thresh_emu(const float* __restrict__ temp,
                                                  float* __restrict__ thresh32) {
    __shared__ float red[128];
    int l = threadIdx.x, b = blockIdx.x;
    red[l] = pw128(&temp[(b << 14) + l * 128]);
    __syncthreads();
    for (int s = 64; s >= 1; s >>= 1) {
        float v = 0.f;
        if (l < s) v = FADD(red[2 * l], red[2 * l + 1]);
        __syncthreads();
        if (l < s) red[l] = v;
        __syncthreads();
    }
    if (l == 0) {
        float sfin = red[0];
        float e = expf_cr(-sfin);                 // np.exp(-s) fp32 (correctly rounded)
        thresh32[b] = FDIV(1.0f, FADD(1.0f, e)); // 1/(1+e)
    }
}

// ---------------------------------------------------------------- binarize (fp32)
__global__ __launch_bounds__(256) void binarize_emu(const float* __restrict__ view32,
                                                    const float* __restrict__ thresh32,
                                                    float* __restrict__ out1) {
    int g = blockIdx.x * 256 + threadIdx.x;
    int e = g * 4;
    int b = e >> 16, i = (e >> 8) & 255, j = e & 255;
    float th = thresh32[b];
    float4 v = *(const float4*)&view32[e];
    float4 o;
    o.x = (FADD(v.x, (i == j + 0) ? 1.f : 0.f) < th) ? 1.f : 0.f;
    o.y = (FADD(v.y, (i == j + 1) ? 1.f : 0.f) < th) ? 1.f : 0.f;
    o.z = (FADD(v.z, (i == j + 2) ? 1.f : 0.f) < th) ? 1.f : 0.f;
    o.w = (FADD(v.w, (i == j + 3) ? 1.f : 0.f) < th) ? 1.f : 0.f;
    *(float4*)&out1[e] = o;
}

// ---------------------------------------------------------------- launch
static inline void ck_launch(const char* name) {
    hipError_t e = hipGetLastError();
    if (e != hipSuccess)
        fprintf(stderr, "[gat] %s launch error %d: %s\n", name, (int)e, hipGetErrorString(e));
}

extern "C" void kernel_launch(void* const* d_in, const int* in_sizes, int n_in,
                              void* d_out, int out_size, void* d_ws, size_t ws_size,
                              hipStream_t stream) {
    const float* X      = (const float*)d_in[0];
    const float* A      = (const float*)d_in[1];
    const float* kern   = (const float*)d_in[2];
    const float* biases = (const float*)d_in[3];
    const float* attn_s = (const float*)d_in[4];
    const float* attn_n = (const float*)d_in[5];
    const float* alpha  = (const float*)d_in[6];

    char* ws = (char*)d_ws;
    unsigned short* feats_bf = (unsigned short*)(ws);             //  33,554,432 B
    float*          feats32  = (float*)(ws + 33554432);           //  67,108,864 B
    float*          view32   = (float*)(ws + 100663296);          //  33,554,432 B
    float*          a_s32    = (float*)(ws + 134217728);          //   1,048,576 B
    float*          a_n32    = (float*)(ws + 135266304);          //   1,048,576 B
    float*          pooled   = (float*)(ws + 136314880);          //   8,388,608 B
    float*          temp     = (float*)(ws + 144703488);          //   8,388,608 B
    float*          thresh32 = (float*)(ws + 153092096);          //         512 B
    unsigned short* wkt      = (unsigned short*)(ws + 153092608); //     524,288 B

    // kern_r2 (8 MB) aliased onto view32's region: dead until attn_emu writes
    // view32, and feats32_emu5 (the only reader) runs strictly before that.
    float*          kern_r2  = (float*)(ws + 100663296);

    float* out0 = (float*)d_out;
    float* out1 = out0 + 16777216;

    repack_w    <<<1024, 256, 0, stream>>>(kern, wkt);              ck_launch("repack_w");
    repack_k32p <<<1024, 256, 0, stream>>>(kern, kern_r2);          ck_launch("repack_k32p");
    gemm_feats  <<<1024, 256, 0, stream>>>(X, wkt, feats_bf);       ck_launch("gemm_feats");
    feats32_emu5<<<2048, 512, 0, stream>>>(X, kern_r2, feats32);    ck_launch("feats32_emu5");
    logits_emu  <<<1024, 256, 0, stream>>>(feats32, attn_s, attn_n, a_s32, a_n32);
                                                                    ck_launch("logits_emu");
    attn_emu    <<<512, 256, 0, stream>>>(A, feats_bf, a_s32, a_n32, biases, out0, view32);
                                                                    ck_launch("attn_emu");
    pool_emu    <<<8192, 256, 0, stream>>>(view32, pooled);         ck_launch("pool_emu");
    temp_emu    <<<8192, 256, 0, stream>>>(pooled, alpha, temp);    ck_launch("temp_emu");
    thresh_emu  <<<128, 128, 0, stream>>>(temp, thresh32);          ck_launch("thresh_emu");
    binarize_emu<<<8192, 256, 0, stream>>>(view32, thresh32, out1); ck_launch("binarize_emu");
}

// Round 6
// 793.755 us; speedup vs baseline: 2.3645x; 2.3645x over previous
//
#include <hip/hip_runtime.h>
#include <hip/hip_bf16.h>
#include <cstdio>
#include <math.h>

// GraphAttention forward, MI355X/gfx950.  Inputs/outputs FLOAT32.
// out0: bf16 MFMA path (PASSES at 2e-2).
// out1: EXACT numpy-fp32 emulation (established R4-R6: fp64 is not enough; the
// binary threshold decisions require bit-identical fp32):
//   - einsum sums (feats over f, logits over k, temp over j): SSE 4-lane 1-acc
//     dot, lane = idx%4, hsum ((a0+a1)+(a2+a3))
//   - np.sum reductions: numpy pairwise_sum, AVX512 base case
//   - exp/sigmoid: correctly-rounded fp32 via fp64 exp
//   - all fp32 ops via __f*_rn (no FMA contraction)
//
// R12: R11's explicit-packed feats32 (fx2 weight loads) REGRESSED 268->1484us:
// the fx2* cast + ternary base select broke the compiler's wave-uniformity
// proof, pushing weights off the scalar s_load path onto per-lane VMEM
// (VALU busy-time 126->647us, VGPR 40->88, occupancy 57->24%). Reverted to
// the proven feats32_emu4 (scalar weight stream, compiler auto-packing).
// Orthogonal win kept: temp_emu read alpha[:,k] at stride 128 (128 uncoalesced
// loads/output, ~1GB L1 traffic); alpha is now transposed once (64KB) and both
// dot streams are contiguous float4s. FADD/FMUL chain order unchanged.

typedef __attribute__((ext_vector_type(8))) short   s16x8;
typedef __attribute__((ext_vector_type(8))) __bf16  bf16x8;
typedef __attribute__((ext_vector_type(4))) float   fx4;

#define FADD __fadd_rn
#define FMUL __fmul_rn
#define FSUB __fsub_rn
#define FDIV __fdiv_rn
#define MASKC (-9999998976.0f)   // fl32(-1e10)

__device__ __forceinline__ fx4 mfma_bf16_16x16x32(s16x8 a, s16x8 b, fx4 c) {
    return __builtin_amdgcn_mfma_f32_16x16x32_bf16(
        __builtin_bit_cast(bf16x8, a), __builtin_bit_cast(bf16x8, b), c, 0, 0, 0);
}
__device__ __forceinline__ unsigned short f2bf(float f) {
    unsigned int x = __builtin_bit_cast(unsigned int, f);
    unsigned int lsb = (x >> 16) & 1u;
    x += 0x7fffu + lsb;
    return (unsigned short)(x >> 16);
}
__device__ __forceinline__ unsigned int pack2(float a, float b) {
    return (unsigned int)f2bf(a) | ((unsigned int)f2bf(b) << 16);
}
__device__ __forceinline__ float expf_cr(float x) {   // correctly-rounded expf
    return (float)exp((double)x);
}

// numpy pairwise_sum base (n=128), AVX512 flavor.
__device__ float pw128(const float* a) {
    float c[16];
#pragma unroll
    for (int l = 0; l < 16; ++l) {
        float t0 = FADD(FADD(a[l], a[16 + l]), FADD(a[32 + l], a[48 + l]));
        float t1 = FADD(FADD(a[64 + l], a[80 + l]), FADD(a[96 + l], a[112 + l]));
        c[l] = FADD(t0, t1);
    }
    float d[8], e[4], f[2];
#pragma unroll
    for (int l = 0; l < 8; ++l) d[l] = FADD(c[l], c[l + 8]);
#pragma unroll
    for (int l = 0; l < 4; ++l) e[l] = FADD(d[l], d[l + 4]);
#pragma unroll
    for (int l = 0; l < 2; ++l) f[l] = FADD(e[l], e[l + 2]);
    return FADD(f[0], f[1]);
}

// ---------------------------------------------------------------- out0 support
__global__ __launch_bounds__(256) void repack_w(const float* __restrict__ kern,
                                                unsigned short* __restrict__ wkt) {
    int t = blockIdx.x * 256 + threadIdx.x;
    int n = t >> 9, f = t & 511;
    int h = n >> 6, k = n & 63;
    wkt[t] = f2bf(kern[(h * 512 + f) * 64 + k]);
}

// fp32 repack for feats32_emu4: kern_r[((h*8+kg)*512+f)*8 + kk]
__global__ __launch_bounds__(256) void repack_k32(const float* __restrict__ kern,
                                                  float* __restrict__ kern_r) {
    int t = blockIdx.x * 256 + threadIdx.x;      // 262,144
    int kk = t & 7, f = (t >> 3) & 511, kgh = t >> 12;
    int kg = kgh & 7, h = kgh >> 3;
    kern_r[t] = kern[(h * 512 + f) * 64 + kg * 8 + kk];
}

// alpha transpose: alphaT[k*128+j] = alpha[j*128+k]
__global__ __launch_bounds__(256) void transpose_alpha(const float* __restrict__ alpha,
                                                       float* __restrict__ alphaT) {
    int t = blockIdx.x * 256 + threadIdx.x;      // 16,384
    int j = t & 127, k = t >> 7;
    alphaT[k * 128 + j] = alpha[j * 128 + k];
}

#define BK 32
__global__ __launch_bounds__(256) void gemm_feats(const float* __restrict__ X,
                                                  const unsigned short* __restrict__ Wkt,
                                                  unsigned short* __restrict__ feats_bf) {
    __shared__ alignas(16) unsigned short As[128 * BK];
    __shared__ alignas(16) unsigned short Bs[128 * BK];
    const int tid = threadIdx.x;
    const int mb = blockIdx.x >> 2, nb = blockIdx.x & 3;
    const int m0 = mb * 128, n0 = nb * 128;
    const int w = tid >> 6, lane = tid & 63;
    const int mw = (w & 1) * 64, nw = (w >> 1) * 64;
    const int lr = lane & 15, lq = lane >> 4;
    const int srow = tid >> 2, scol = (tid & 3) * 8;

    fx4 acc[4][4] = {};
    for (int k0 = 0; k0 < 512; k0 += BK) {
        __syncthreads();
        {
            const float* xr0 = &X[(m0 + srow) * 512 + k0 + scol];
            const float* xr1 = &X[(m0 + srow + 64) * 512 + k0 + scol];
            float4 a0 = *(const float4*)xr0, a1 = *(const float4*)(xr0 + 4);
            float4 b0 = *(const float4*)xr1, b1 = *(const float4*)(xr1 + 4);
            uint4 p0 = { pack2(a0.x, a0.y), pack2(a0.z, a0.w), pack2(a1.x, a1.y), pack2(a1.z, a1.w) };
            uint4 p1 = { pack2(b0.x, b0.y), pack2(b0.z, b0.w), pack2(b1.x, b1.y), pack2(b1.z, b1.w) };
            *(uint4*)&As[srow * BK + scol]        = p0;
            *(uint4*)&As[(srow + 64) * BK + scol] = p1;
            *(uint4*)&Bs[srow * BK + scol]        = *(const uint4*)&Wkt[(n0 + srow) * 512 + k0 + scol];
            *(uint4*)&Bs[(srow + 64) * BK + scol] = *(const uint4*)&Wkt[(n0 + srow + 64) * 512 + k0 + scol];
        }
        __syncthreads();
        s16x8 a[4], bb[4];
#pragma unroll
        for (int i = 0; i < 4; ++i) a[i]  = *(const s16x8*)&As[(mw + i * 16 + lr) * BK + lq * 8];
#pragma unroll
        for (int i = 0; i < 4; ++i) bb[i] = *(const s16x8*)&Bs[(nw + i * 16 + lr) * BK + lq * 8];
#pragma unroll
        for (int i = 0; i < 4; ++i)
#pragma unroll
            for (int j = 0; j < 4; ++j)
                acc[i][j] = mfma_bf16_16x16x32(a[i], bb[j], acc[i][j]);
    }
#pragma unroll
    for (int i = 0; i < 4; ++i)
#pragma unroll
        for (int j = 0; j < 4; ++j) {
            int col  = n0 + nw + j * 16 + lr;
            int rowb = m0 + mw + i * 16 + lq * 4;
#pragma unroll
            for (int r = 0; r < 4; ++r)
                feats_bf[(rowb + r) * 512 + col] = f2bf(acc[i][j][r]);
        }
}

// ---------------------------------------------------------------- feats32 (np emu, v4 — proven)
#define FCH 128
#define XS_STRIDE 132   // floats; 16B-aligned
__global__ __launch_bounds__(512) void feats32_emu4(const float* __restrict__ X,
                                                    const float* __restrict__ kern_r,
                                                    float* __restrict__ feats32) {
    __shared__ alignas(16) float Xs[64 * XS_STRIDE];   // 33,792 B
    const int tid = threadIdx.x;
    const int hg = blockIdx.x >> 9;          // 0..3  (grid = 4 * 512)
    const int rb = blockIdx.x & 511;         // 0..511
    const int h0 = hg * 2;
    const int lane = tid & 63;
    const int kg = __builtin_amdgcn_readfirstlane(tid >> 6);   // wave-uniform 0..7
    const int k0 = kg * 8;
    const int row0 = rb * 64;
    const int srow = tid >> 3, sseg = tid & 7;   // staging map: 64 rows x 8 segs

    float acc[2][8][4];
#pragma unroll
    for (int hh = 0; hh < 2; ++hh)
#pragma unroll
        for (int q = 0; q < 8; ++q)
#pragma unroll
            for (int l = 0; l < 4; ++l) acc[hh][q][l] = 0.f;

    // per-(h,kg) weight slices, 16KB each, contiguous
    const float* __restrict__ kp0 = &kern_r[(((h0 + 0) * 8 + kg) * 512) * 8];
    const float* __restrict__ kp1 = &kern_r[(((h0 + 1) * 8 + kg) * 512) * 8];

    for (int fc = 0; fc < 512; fc += FCH) {
        __syncthreads();
        {
            const float* gp = &X[(row0 + srow) * 512 + fc + sseg * 16];
            float* sp = &Xs[srow * XS_STRIDE + sseg * 16];
#pragma unroll
            for (int i = 0; i < 4; ++i)
                *(float4*)&sp[i * 4] = *(const float4*)&gp[i * 4];
        }
        __syncthreads();

        const float* __restrict__ xrow = &Xs[lane * XS_STRIDE];
        for (int fo = 0; fo < FCH; fo += 8) {
            float xv[8];
            {
                float4 xa = *(const float4*)&xrow[fo];
                float4 xb = *(const float4*)&xrow[fo + 4];
                xv[0] = xa.x; xv[1] = xa.y; xv[2] = xa.z; xv[3] = xa.w;
                xv[4] = xb.x; xv[5] = xb.y; xv[6] = xb.z; xv[7] = xb.w;
            }
#pragma unroll
            for (int hh = 0; hh < 2; ++hh) {
                const float* __restrict__ kp = (hh == 0 ? kp0 : kp1) + (fc + fo) * 8;
                float w[8][8];   // w[j][q] = kern[h][fc+fo+j][k0+q]; 256B contiguous
#pragma unroll
                for (int j = 0; j < 8; ++j) {
                    float4 lo = *(const float4*)&kp[j * 8];
                    float4 hi = *(const float4*)&kp[j * 8 + 4];
                    w[j][0] = lo.x; w[j][1] = lo.y; w[j][2] = lo.z; w[j][3] = lo.w;
                    w[j][4] = hi.x; w[j][5] = hi.y; w[j][6] = hi.z; w[j][7] = hi.w;
                }
#pragma unroll
                for (int q = 0; q < 8; ++q) {
                    acc[hh][q][0] = FADD(acc[hh][q][0], FMUL(xv[0], w[0][q]));
                    acc[hh][q][1] = FADD(acc[hh][q][1], FMUL(xv[1], w[1][q]));
                    acc[hh][q][2] = FADD(acc[hh][q][2], FMUL(xv[2], w[2][q]));
                    acc[hh][q][3] = FADD(acc[hh][q][3], FMUL(xv[3], w[3][q]));
                    acc[hh][q][0] = FADD(acc[hh][q][0], FMUL(xv[4], w[4][q]));
                    acc[hh][q][1] = FADD(acc[hh][q][1], FMUL(xv[5], w[5][q]));
                    acc[hh][q][2] = FADD(acc[hh][q][2], FMUL(xv[6], w[6][q]));
                    acc[hh][q][3] = FADD(acc[hh][q][3], FMUL(xv[7], w[7][q]));
                }
            }
        }
    }

#pragma unroll
    for (int hh = 0; hh < 2; ++hh) {
        float* __restrict__ op = &feats32[((h0 + hh) * 32768 + row0 + lane) * 64 + k0];
        float4 o0, o1;
        o0.x = FADD(FADD(acc[hh][0][0], acc[hh][0][1]), FADD(acc[hh][0][2], acc[hh][0][3]));
        o0.y = FADD(FADD(acc[hh][1][0], acc[hh][1][1]), FADD(acc[hh][1][2], acc[hh][1][3]));
        o0.z = FADD(FADD(acc[hh][2][0], acc[hh][2][1]), FADD(acc[hh][2][2], acc[hh][2][3]));
        o0.w = FADD(FADD(acc[hh][3][0], acc[hh][3][1]), FADD(acc[hh][3][2], acc[hh][3][3]));
        o1.x = FADD(FADD(acc[hh][4][0], acc[hh][4][1]), FADD(acc[hh][4][2], acc[hh][4][3]));
        o1.y = FADD(FADD(acc[hh][5][0], acc[hh][5][1]), FADD(acc[hh][5][2], acc[hh][5][3]));
        o1.z = FADD(FADD(acc[hh][6][0], acc[hh][6][1]), FADD(acc[hh][6][2], acc[hh][6][3]));
        o1.w = FADD(FADD(acc[hh][7][0], acc[hh][7][1]), FADD(acc[hh][7][2], acc[hh][7][3]));
        *(float4*)&op[0] = o0;
        *(float4*)&op[4] = o1;
    }
}

// ---------------------------------------------------------------- logits (np emu)
__device__ float sse_dot64(const float* __restrict__ x, const float* __restrict__ y) {
    float a0 = 0.f, a1 = 0.f, a2 = 0.f, a3 = 0.f;
    for (int i = 0; i < 64; i += 8) {
        a0 = FADD(a0, FMUL(x[i + 0], y[i + 0]));
        a1 = FADD(a1, FMUL(x[i + 1], y[i + 1]));
        a2 = FADD(a2, FMUL(x[i + 2], y[i + 2]));
        a3 = FADD(a3, FMUL(x[i + 3], y[i + 3]));
        a0 = FADD(a0, FMUL(x[i + 4], y[i + 4]));
        a1 = FADD(a1, FMUL(x[i + 5], y[i + 5]));
        a2 = FADD(a2, FMUL(x[i + 6], y[i + 6]));
        a3 = FADD(a3, FMUL(x[i + 7], y[i + 7]));
    }
    return FADD(FADD(a0, a1), FADD(a2, a3));
}

__global__ __launch_bounds__(256) void logits_emu(const float* __restrict__ feats32,
                                                  const float* __restrict__ attn_s,
                                                  const float* __restrict__ attn_n,
                                                  float* __restrict__ a_s32,
                                                  float* __restrict__ a_n32) {
    int t = blockIdx.x * 256 + threadIdx.x;      // 262,144
    int row = t & 32767, h = t >> 15;
    const float* fr = &feats32[(h * 32768 + row) * 64];
    a_s32[h * 32768 + row] = sse_dot64(fr, &attn_s[h * 64]);
    a_n32[h * 32768 + row] = sse_dot64(fr, &attn_n[h * 64]);
}

// ---------------------------------------------------------------- attention (np-fp32 emu, v2)
#define VT_STRIDE 264
__global__ __launch_bounds__(256) void attn_emu(const float* __restrict__ A,
                                                const unsigned short* __restrict__ feats_bf,
                                                const float* __restrict__ a_s32,
                                                const float* __restrict__ a_n32,
                                                const float* __restrict__ biases,
                                                float* __restrict__ out0,
                                                float* __restrict__ view32) {
    __shared__ alignas(16) unsigned short Vt[64 * VT_STRIDE];   // 33792 B
    __shared__ alignas(16) unsigned int   Abits[64][8];         //  2048 B
    __shared__ alignas(16) float an_l[8][256];                  //  8192 B
    __shared__ alignas(16) float as_l[8][64];                   //  2048 B  = 46080 B

    const int tid = threadIdx.x;
    const int b = blockIdx.x >> 2;
    const int row0 = (blockIdx.x & 3) * 64;
    const int w = tid >> 6, lane = tid & 63;
    const int m = lane & 15, jq = lane >> 4;

    // stage adjacency as bitmask: 64 rows x 256 bits
    {
        int i = tid >> 2, sg = tid & 3;
        const float* ar = &A[(((b << 8) + row0 + i) << 8) + sg * 64];
        unsigned int w0 = 0, w1 = 0;
#pragma unroll
        for (int q = 0; q < 8; ++q) {
            float4 av = *(const float4*)&ar[q * 4];
            unsigned int m4 = (av.x != 0.f ? 1u : 0u) | (av.y != 0.f ? 2u : 0u) |
                              (av.z != 0.f ? 4u : 0u) | (av.w != 0.f ? 8u : 0u);
            w0 |= m4 << (q * 4);
        }
#pragma unroll
        for (int q = 8; q < 16; ++q) {
            float4 av = *(const float4*)&ar[q * 4];
            unsigned int m4 = (av.x != 0.f ? 1u : 0u) | (av.y != 0.f ? 2u : 0u) |
                              (av.z != 0.f ? 4u : 0u) | (av.w != 0.f ? 8u : 0u);
            w1 |= m4 << ((q - 8) * 4);
        }
        Abits[i][sg * 2]     = w0;
        Abits[i][sg * 2 + 1] = w1;
    }
    // stage logits (all heads)
    for (int idx = tid; idx < 2048; idx += 256) {
        int h = idx >> 8, j = idx & 255;
        an_l[h][j] = a_n32[h * 32768 + (b << 8) + j];
    }
    for (int idx = tid; idx < 512; idx += 256) {
        int h = idx >> 6, i = idx & 63;
        as_l[h][i] = a_s32[h * 32768 + (b << 8) + row0 + i];
    }
    __syncthreads();

    const int i_ln = w * 16 + m;
    const int myrow = row0 + i_ln;
    unsigned int abits[8];
#pragma unroll
    for (int u = 0; u < 8; ++u) abits[u] = Abits[i_ln][u];

    float view_acc[8][8] = {};

    for (int h = 0; h < 8; ++h) {
        __syncthreads();
        {   // stage V^T for this head: 16B global loads, scalar LDS writes
            int jb = w;
#pragma unroll
            for (int it = 0; it < 8; ++it) {
                int j  = jb * 64 + it * 8 + (lane >> 3);
                int kg = lane & 7;
                s16x8 v8 = *(const s16x8*)&feats_bf[(((b << 8) + j) << 9) + (h << 6) + kg * 8];
#pragma unroll
                for (int u = 0; u < 8; ++u)
                    Vt[(kg * 8 + u) * VT_STRIDE + j] = (unsigned short)v8[u];
            }
        }
        __syncthreads();

        const float asv = as_l[h][i_ln];

        // ---- logits once, tracking local max
        float ev[8][8];
        float Mloc = -3.4e38f;
#pragma unroll
        for (int kb = 0; kb < 8; ++kb) {
            int jbase = kb * 32 + jq * 8;
            float4 an0 = *(const float4*)&an_l[h][jbase];
            float4 an1 = *(const float4*)&an_l[h][jbase + 4];
            float anv[8] = { an0.x, an0.y, an0.z, an0.w, an1.x, an1.y, an1.z, an1.w };
            unsigned int mb = (abits[kb] >> (jq * 8)) & 0xffu;
#pragma unroll
            for (int t = 0; t < 8; ++t) {
                float lg = FADD(asv, anv[t]);
                float lr = lg > 0.f ? lg : FMUL(0.2f, lg);
                float v  = (mb & (1u << t)) ? lr : FADD(lr, MASKC);
                ev[kb][t] = v;
                Mloc = fmaxf(Mloc, v);
            }
        }
        // ---- M: order-free cross-lane max over the row's 4 lanes
        Mloc = fmaxf(Mloc, __shfl_xor(Mloc, 16, 64));
        Mloc = fmaxf(Mloc, __shfl_xor(Mloc, 32, 64));
        const float Mi = Mloc;

        // ---- exp ONCE
#pragma unroll
        for (int kb = 0; kb < 8; ++kb)
#pragma unroll
            for (int t = 0; t < 8; ++t)
                ev[kb][t] = expf_cr(FSUB(ev[kb][t], Mi));

        // ---- S: numpy pairwise tree via shuffles (exact; FADD commutative)
        float blkS[2];
#pragma unroll
        for (int blk = 0; blk < 2; ++blk) {
            float d[8];
#pragma unroll
            for (int t = 0; t < 8; ++t) {
                float s0 = FADD(ev[blk * 4 + 0][t], __shfl_xor(ev[blk * 4 + 0][t], 32, 64));
                float s1 = FADD(ev[blk * 4 + 1][t], __shfl_xor(ev[blk * 4 + 1][t], 32, 64));
                float s2 = FADD(ev[blk * 4 + 2][t], __shfl_xor(ev[blk * 4 + 2][t], 32, 64));
                float s3 = FADD(ev[blk * 4 + 3][t], __shfl_xor(ev[blk * 4 + 3][t], 32, 64));
                float cc = FADD(FADD(s0, s1), FADD(s2, s3));   // c[l]
                d[t] = FADD(cc, __shfl_xor(cc, 16, 64));       // d[l] = c[l]+c[l+8]
            }
            float e4[4], f2[2];
#pragma unroll
            for (int t = 0; t < 4; ++t) e4[t] = FADD(d[t], d[t + 4]);
            f2[0] = FADD(e4[0], e4[2]);
            f2[1] = FADD(e4[1], e4[3]);
            blkS[blk] = FADD(f2[0], f2[1]);
        }
        const float Si = FADD(blkS[0], blkS[1]);

        // ---- p, view accumulate, PV MFMA
        s16x8 pfrag[8];
#pragma unroll
        for (int kb = 0; kb < 8; ++kb) {
            s16x8 pf;
#pragma unroll
            for (int t = 0; t < 8; ++t) {
                float p = FDIV(ev[kb][t], Si);
                view_acc[kb][t] = FADD(view_acc[kb][t], FMUL(p, 0.125f));
                pf[t] = (short)f2bf(p);
            }
            pfrag[kb] = pf;
        }

        fx4 acc[4] = {};
#pragma unroll
        for (int kb = 0; kb < 8; ++kb) {
            int jo = kb * 32 + jq * 8;
#pragma unroll
            for (int nf = 0; nf < 4; ++nf) {
                s16x8 vf = *(const s16x8*)&Vt[(nf * 16 + m) * VT_STRIDE + jo];
                acc[nf] = mfma_bf16_16x16x32(pfrag[kb], vf, acc[nf]);
            }
        }
#pragma unroll
        for (int nf = 0; nf < 4; ++nf) {
            float bias = biases[h * 64 + nf * 16 + m];
#pragma unroll
            for (int r = 0; r < 4; ++r) {
                float val = acc[nf][r] + bias;
                val = val > 0.f ? val : 0.f;
                int gi = (b << 8) + row0 + w * 16 + jq * 4 + r;
                out0[gi * 512 + h * 64 + nf * 16 + m] = val;
            }
        }
    }

#pragma unroll
    for (int kb = 0; kb < 8; ++kb) {
        int base = (((b << 8) + myrow) << 8) + kb * 32 + jq * 8;
        float4 v0, v1;
        v0.x = view_acc[kb][0]; v0.y = view_acc[kb][1]; v0.z = view_acc[kb][2]; v0.w = view_acc[kb][3];
        v1.x = view_acc[kb][4]; v1.y = view_acc[kb][5]; v1.z = view_acc[kb][6]; v1.w = view_acc[kb][7];
        *(float4*)&view32[base]     = v0;
        *(float4*)&view32[base + 4] = v1;
    }
}

// ---------------------------------------------------------------- pool / temp / thresh
__global__ __launch_bounds__(256) void pool_emu(const float* __restrict__ view32,
                                                float* __restrict__ pooled) {
    int t = blockIdx.x * 256 + threadIdx.x;      // 2,097,152
    int j = t & 127, i = (t >> 7) & 127, b = t >> 14;
    const float* p = &view32[(b << 16) + (2 * i) * 256 + 2 * j];
    pooled[t] = fmaxf(fmaxf(p[0], p[1]), fmaxf(p[256], p[257]));
}

// temp[b,i,k] = SSE dot over j=0..127: pooled row (contig) x alphaT row k (contig).
// Same FADD/FMUL chain as before (lane=j%4, j ascending, pair j/j+4).
__global__ __launch_bounds__(256) void temp_emu(const float* __restrict__ pooled,
                                                const float* __restrict__ alphaT,
                                                float* __restrict__ temp) {
    int t = blockIdx.x * 256 + threadIdx.x;      // 2,097,152
    int k = t & 127, i = (t >> 7) & 127, b = t >> 14;
    const float* pr = &pooled[(b << 14) + i * 128];
    const float* ap = &alphaT[k * 128];           // contiguous over j
    float a0 = 0.f, a1 = 0.f, a2 = 0.f, a3 = 0.f;
    for (int j = 0; j < 128; j += 8) {
        float4 p0 = *(const float4*)&pr[j];
        float4 p1 = *(const float4*)&pr[j + 4];
        float4 q0 = *(const float4*)&ap[j];
        float4 q1 = *(const float4*)&ap[j + 4];
        a0 = FADD(a0, FMUL(p0.x, q0.x));
        a1 = FADD(a1, FMUL(p0.y, q0.y));
        a2 = FADD(a2, FMUL(p0.z, q0.z));
        a3 = FADD(a3, FMUL(p0.w, q0.w));
        a0 = FADD(a0, FMUL(p1.x, q1.x));
        a1 = FADD(a1, FMUL(p1.y, q1.y));
        a2 = FADD(a2, FMUL(p1.z, q1.z));
        a3 = FADD(a3, FMUL(p1.w, q1.w));
    }
    temp[t] = FADD(FADD(a0, a1), FADD(a2, a3));
}

// s[b] = numpy pairwise over 16384 (128 leaves of pw128, balanced binary tree)
__global__ __launch_bounds__(128) void thresh_emu(const float* __restrict__ temp,
                                                  float* __restrict__ thresh32) {
    __shared__ float red[128];
    int l = threadIdx.x, b = blockIdx.x;
    red[l] = pw128(&temp[(b << 14) + l * 128]);
    __syncthreads();
    for (int s = 64; s >= 1; s >>= 1) {
        float v = 0.f;
        if (l < s) v = FADD(red[2 * l], red[2 * l + 1]);
        __syncthreads();
        if (l < s) red[l] = v;
        __syncthreads();
    }
    if (l == 0) {
        float sfin = red[0];
        float e = expf_cr(-sfin);                 // np.exp(-s) fp32 (correctly rounded)
        thresh32[b] = FDIV(1.0f, FADD(1.0f, e)); // 1/(1+e)
    }
}

// ---------------------------------------------------------------- binarize (fp32)
__global__ __launch_bounds__(256) void binarize_emu(const float* __restrict__ view32,
                                                    const float* __restrict__ thresh32,
                                                    float* __restrict__ out1) {
    int g = blockIdx.x * 256 + threadIdx.x;
    int e = g * 4;
    int b = e >> 16, i = (e >> 8) & 255, j = e & 255;
    float th = thresh32[b];
    float4 v = *(const float4*)&view32[e];
    float4 o;
    o.x = (FADD(v.x, (i == j + 0) ? 1.f : 0.f) < th) ? 1.f : 0.f;
    o.y = (FADD(v.y, (i == j + 1) ? 1.f : 0.f) < th) ? 1.f : 0.f;
    o.z = (FADD(v.z, (i == j + 2) ? 1.f : 0.f) < th) ? 1.f : 0.f;
    o.w = (FADD(v.w, (i == j + 3) ? 1.f : 0.f) < th) ? 1.f : 0.f;
    *(float4*)&out1[e] = o;
}

// ---------------------------------------------------------------- launch
static inline void ck_launch(const char* name) {
    hipError_t e = hipGetLastError();
    if (e != hipSuccess)
        fprintf(stderr, "[gat] %s launch error %d: %s\n", name, (int)e, hipGetErrorString(e));
}

extern "C" void kernel_launch(void* const* d_in, const int* in_sizes, int n_in,
                              void* d_out, int out_size, void* d_ws, size_t ws_size,
                              hipStream_t stream) {
    const float* X      = (const float*)d_in[0];
    const float* A      = (const float*)d_in[1];
    const float* kern   = (const float*)d_in[2];
    const float* biases = (const float*)d_in[3];
    const float* attn_s = (const float*)d_in[4];
    const float* attn_n = (const float*)d_in[5];
    const float* alpha  = (const float*)d_in[6];

    char* ws = (char*)d_ws;
    unsigned short* feats_bf = (unsigned short*)(ws);             //  33,554,432 B
    float*          feats32  = (float*)(ws + 33554432);           //  67,108,864 B
    float*          view32   = (float*)(ws + 100663296);          //  33,554,432 B
    float*          a_s32    = (float*)(ws + 134217728);          //   1,048,576 B
    float*          a_n32    = (float*)(ws + 135266304);          //   1,048,576 B
    float*          pooled   = (float*)(ws + 136314880);          //   8,388,608 B
    float*          temp     = (float*)(ws + 144703488);          //   8,388,608 B
    float*          thresh32 = (float*)(ws + 153092096);          //         512 B
    unsigned short* wkt      = (unsigned short*)(ws + 153092608); //     524,288 B
    float*          alphaT   = (float*)(ws + 153616896);          //      65,536 B

    // kern_r (8 MB) aliased onto view32's region: dead until attn_emu writes
    // view32, and feats32_emu4 (the only reader) runs strictly before that.
    float*          kern_r   = (float*)(ws + 100663296);

    float* out0 = (float*)d_out;
    float* out1 = out0 + 16777216;

    repack_w    <<<1024, 256, 0, stream>>>(kern, wkt);              ck_launch("repack_w");
    repack_k32  <<<1024, 256, 0, stream>>>(kern, kern_r);           ck_launch("repack_k32");
    transpose_alpha<<<64, 256, 0, stream>>>(alpha, alphaT);         ck_launch("transpose_alpha");
    gemm_feats  <<<1024, 256, 0, stream>>>(X, wkt, feats_bf);       ck_launch("gemm_feats");
    feats32_emu4<<<2048, 512, 0, stream>>>(X, kern_r, feats32);     ck_launch("feats32_emu4");
    logits_emu  <<<1024, 256, 0, stream>>>(feats32, attn_s, attn_n, a_s32, a_n32);
                                                                    ck_launch("logits_emu");
    attn_emu    <<<512, 256, 0, stream>>>(A, feats_bf, a_s32, a_n32, biases, out0, view32);
                                                                    ck_launch("attn_emu");
    pool_emu    <<<8192, 256, 0, stream>>>(view32, pooled);         ck_launch("pool_emu");
    temp_emu    <<<8192, 256, 0, stream>>>(pooled, alphaT, temp);   ck_launch("temp_emu");
    thresh_emu  <<<128, 128, 0, stream>>>(temp, thresh32);          ck_launch("thresh_emu");
    binarize_emu<<<8192, 256, 0, stream>>>(view32, thresh32, out1); ck_launch("binarize_emu");
}

// Round 7
// 682.077 us; speedup vs baseline: 2.7516x; 1.1637x over previous
//
#include <hip/hip_runtime.h>
#include <hip/hip_bf16.h>
#include <cstdio>
#include <math.h>

// GraphAttention forward, MI355X/gfx950.  Inputs/outputs FLOAT32.
// out0: bf16 MFMA path (PASSES at 2e-2).
// out1: EXACT numpy-fp32 emulation (established R4-R6: fp64 is not enough; the
// binary threshold decisions require bit-identical fp32):
//   - einsum sums (feats over f, logits over k, temp over j): SSE 4-lane 1-acc
//     dot, lane = idx%4, hsum ((a0+a1)+(a2+a3))
//   - np.sum reductions: numpy pairwise_sum, AVX512 base case
//   - exp/sigmoid: correctly-rounded fp32 via fp64 exp
//   - all fp32 ops via __f*_rn (no FMA contraction)
//
// R13: (1) R12's alphaT transpose was a PESSIMIZATION (+88us): old temp_emu was
// already coalesced ACROSS LANES (k varies per lane -> alpha[j*128+k] contiguous;
// pooled row broadcast). Reverted to the per-wave-optimal layout.
// (2) feats32: 127us VALU-busy / 146us stalled. Applied ONLY the double-buffer
// part of R11's emu5 (its regression was the vector-weight type-punning, not
// DB): FCH=64, Xs[2], next-chunk X loads issued before compute, one barrier
// per chunk. Weight path (scalar w[8][8] float4, ternary kp select) is
// byte-identical to emu4's. Arithmetic chains untouched -> bit-exact.

typedef __attribute__((ext_vector_type(8))) short   s16x8;
typedef __attribute__((ext_vector_type(8))) __bf16  bf16x8;
typedef __attribute__((ext_vector_type(4))) float   fx4;

#define FADD __fadd_rn
#define FMUL __fmul_rn
#define FSUB __fsub_rn
#define FDIV __fdiv_rn
#define MASKC (-9999998976.0f)   // fl32(-1e10)

__device__ __forceinline__ fx4 mfma_bf16_16x16x32(s16x8 a, s16x8 b, fx4 c) {
    return __builtin_amdgcn_mfma_f32_16x16x32_bf16(
        __builtin_bit_cast(bf16x8, a), __builtin_bit_cast(bf16x8, b), c, 0, 0, 0);
}
__device__ __forceinline__ unsigned short f2bf(float f) {
    unsigned int x = __builtin_bit_cast(unsigned int, f);
    unsigned int lsb = (x >> 16) & 1u;
    x += 0x7fffu + lsb;
    return (unsigned short)(x >> 16);
}
__device__ __forceinline__ unsigned int pack2(float a, float b) {
    return (unsigned int)f2bf(a) | ((unsigned int)f2bf(b) << 16);
}
__device__ __forceinline__ float expf_cr(float x) {   // correctly-rounded expf
    return (float)exp((double)x);
}

// numpy pairwise_sum base (n=128), AVX512 flavor.
__device__ float pw128(const float* a) {
    float c[16];
#pragma unroll
    for (int l = 0; l < 16; ++l) {
        float t0 = FADD(FADD(a[l], a[16 + l]), FADD(a[32 + l], a[48 + l]));
        float t1 = FADD(FADD(a[64 + l], a[80 + l]), FADD(a[96 + l], a[112 + l]));
        c[l] = FADD(t0, t1);
    }
    float d[8], e[4], f[2];
#pragma unroll
    for (int l = 0; l < 8; ++l) d[l] = FADD(c[l], c[l + 8]);
#pragma unroll
    for (int l = 0; l < 4; ++l) e[l] = FADD(d[l], d[l + 4]);
#pragma unroll
    for (int l = 0; l < 2; ++l) f[l] = FADD(e[l], e[l + 2]);
    return FADD(f[0], f[1]);
}

// ---------------------------------------------------------------- out0 support
__global__ __launch_bounds__(256) void repack_w(const float* __restrict__ kern,
                                                unsigned short* __restrict__ wkt) {
    int t = blockIdx.x * 256 + threadIdx.x;
    int n = t >> 9, f = t & 511;
    int h = n >> 6, k = n & 63;
    wkt[t] = f2bf(kern[(h * 512 + f) * 64 + k]);
}

// fp32 repack for feats32: kern_r[((h*8+kg)*512+f)*8 + kk]
__global__ __launch_bounds__(256) void repack_k32(const float* __restrict__ kern,
                                                  float* __restrict__ kern_r) {
    int t = blockIdx.x * 256 + threadIdx.x;      // 262,144
    int kk = t & 7, f = (t >> 3) & 511, kgh = t >> 12;
    int kg = kgh & 7, h = kgh >> 3;
    kern_r[t] = kern[(h * 512 + f) * 64 + kg * 8 + kk];
}

#define BK 32
__global__ __launch_bounds__(256) void gemm_feats(const float* __restrict__ X,
                                                  const unsigned short* __restrict__ Wkt,
                                                  unsigned short* __restrict__ feats_bf) {
    __shared__ alignas(16) unsigned short As[128 * BK];
    __shared__ alignas(16) unsigned short Bs[128 * BK];
    const int tid = threadIdx.x;
    const int mb = blockIdx.x >> 2, nb = blockIdx.x & 3;
    const int m0 = mb * 128, n0 = nb * 128;
    const int w = tid >> 6, lane = tid & 63;
    const int mw = (w & 1) * 64, nw = (w >> 1) * 64;
    const int lr = lane & 15, lq = lane >> 4;
    const int srow = tid >> 2, scol = (tid & 3) * 8;

    fx4 acc[4][4] = {};
    for (int k0 = 0; k0 < 512; k0 += BK) {
        __syncthreads();
        {
            const float* xr0 = &X[(m0 + srow) * 512 + k0 + scol];
            const float* xr1 = &X[(m0 + srow + 64) * 512 + k0 + scol];
            float4 a0 = *(const float4*)xr0, a1 = *(const float4*)(xr0 + 4);
            float4 b0 = *(const float4*)xr1, b1 = *(const float4*)(xr1 + 4);
            uint4 p0 = { pack2(a0.x, a0.y), pack2(a0.z, a0.w), pack2(a1.x, a1.y), pack2(a1.z, a1.w) };
            uint4 p1 = { pack2(b0.x, b0.y), pack2(b0.z, b0.w), pack2(b1.x, b1.y), pack2(b1.z, b1.w) };
            *(uint4*)&As[srow * BK + scol]        = p0;
            *(uint4*)&As[(srow + 64) * BK + scol] = p1;
            *(uint4*)&Bs[srow * BK + scol]        = *(const uint4*)&Wkt[(n0 + srow) * 512 + k0 + scol];
            *(uint4*)&Bs[(srow + 64) * BK + scol] = *(const uint4*)&Wkt[(n0 + srow + 64) * 512 + k0 + scol];
        }
        __syncthreads();
        s16x8 a[4], bb[4];
#pragma unroll
        for (int i = 0; i < 4; ++i) a[i]  = *(const s16x8*)&As[(mw + i * 16 + lr) * BK + lq * 8];
#pragma unroll
        for (int i = 0; i < 4; ++i) bb[i] = *(const s16x8*)&Bs[(nw + i * 16 + lr) * BK + lq * 8];
#pragma unroll
        for (int i = 0; i < 4; ++i)
#pragma unroll
            for (int j = 0; j < 4; ++j)
                acc[i][j] = mfma_bf16_16x16x32(a[i], bb[j], acc[i][j]);
    }
#pragma unroll
    for (int i = 0; i < 4; ++i)
#pragma unroll
        for (int j = 0; j < 4; ++j) {
            int col  = n0 + nw + j * 16 + lr;
            int rowb = m0 + mw + i * 16 + lq * 4;
#pragma unroll
            for (int r = 0; r < 4; ++r)
                feats_bf[(rowb + r) * 512 + col] = f2bf(acc[i][j][r]);
        }
}

// ---------------------------------------------------------------- feats32 (np emu, v6)
// emu4's proven weight path + X LDS double-buffer (FCH=64, one barrier/chunk).
#define FCH6 64
#define XS6_STRIDE 68   // floats; 16B-aligned
__global__ __launch_bounds__(512) void feats32_emu6(const float* __restrict__ X,
                                                    const float* __restrict__ kern_r,
                                                    float* __restrict__ feats32) {
    __shared__ alignas(16) float Xs[2][64 * XS6_STRIDE];   // 34,816 B
    const int tid = threadIdx.x;
    const int hg = blockIdx.x >> 9;          // 0..3  (grid = 4 * 512)
    const int rb = blockIdx.x & 511;         // 0..511
    const int h0 = hg * 2;
    const int lane = tid & 63;
    const int kg = __builtin_amdgcn_readfirstlane(tid >> 6);   // wave-uniform 0..7
    const int k0 = kg * 8;
    const int row0 = rb * 64;
    const int srow = tid >> 3, sseg = tid & 7;   // staging: 64 rows x 8 segs x 8 floats

    float acc[2][8][4];
#pragma unroll
    for (int hh = 0; hh < 2; ++hh)
#pragma unroll
        for (int q = 0; q < 8; ++q)
#pragma unroll
            for (int l = 0; l < 4; ++l) acc[hh][q][l] = 0.f;

    // per-(h,kg) weight slices, 16KB each, contiguous
    const float* __restrict__ kp0 = &kern_r[(((h0 + 0) * 8 + kg) * 512) * 8];
    const float* __restrict__ kp1 = &kern_r[(((h0 + 1) * 8 + kg) * 512) * 8];

    // prologue: stage chunk 0
    {
        const float* gp = &X[(row0 + srow) * 512 + sseg * 8];
        *(float4*)&Xs[0][srow * XS6_STRIDE + sseg * 8]     = *(const float4*)gp;
        *(float4*)&Xs[0][srow * XS6_STRIDE + sseg * 8 + 4] = *(const float4*)(gp + 4);
    }
    __syncthreads();

    for (int ch = 0; ch < 8; ++ch) {
        const int fc = ch * FCH6;
        const int cur = ch & 1;
        float4 nx0, nx1;
        if (ch < 7) {   // issue next-chunk global loads; land during compute
            const float* gp = &X[(row0 + srow) * 512 + fc + FCH6 + sseg * 8];
            nx0 = *(const float4*)gp;
            nx1 = *(const float4*)(gp + 4);
        }

        const float* __restrict__ xrow = &Xs[cur][lane * XS6_STRIDE];
        for (int fo = 0; fo < FCH6; fo += 8) {
            float xv[8];
            {
                float4 xa = *(const float4*)&xrow[fo];
                float4 xb = *(const float4*)&xrow[fo + 4];
                xv[0] = xa.x; xv[1] = xa.y; xv[2] = xa.z; xv[3] = xa.w;
                xv[4] = xb.x; xv[5] = xb.y; xv[6] = xb.z; xv[7] = xb.w;
            }
#pragma unroll
            for (int hh = 0; hh < 2; ++hh) {
                const float* __restrict__ kp = (hh == 0 ? kp0 : kp1) + (fc + fo) * 8;
                float w[8][8];   // w[j][q] = kern[h][fc+fo+j][k0+q]; 256B contiguous
#pragma unroll
                for (int j = 0; j < 8; ++j) {
                    float4 lo = *(const float4*)&kp[j * 8];
                    float4 hi = *(const float4*)&kp[j * 8 + 4];
                    w[j][0] = lo.x; w[j][1] = lo.y; w[j][2] = lo.z; w[j][3] = lo.w;
                    w[j][4] = hi.x; w[j][5] = hi.y; w[j][6] = hi.z; w[j][7] = hi.w;
                }
#pragma unroll
                for (int q = 0; q < 8; ++q) {
                    acc[hh][q][0] = FADD(acc[hh][q][0], FMUL(xv[0], w[0][q]));
                    acc[hh][q][1] = FADD(acc[hh][q][1], FMUL(xv[1], w[1][q]));
                    acc[hh][q][2] = FADD(acc[hh][q][2], FMUL(xv[2], w[2][q]));
                    acc[hh][q][3] = FADD(acc[hh][q][3], FMUL(xv[3], w[3][q]));
                    acc[hh][q][0] = FADD(acc[hh][q][0], FMUL(xv[4], w[4][q]));
                    acc[hh][q][1] = FADD(acc[hh][q][1], FMUL(xv[5], w[5][q]));
                    acc[hh][q][2] = FADD(acc[hh][q][2], FMUL(xv[6], w[6][q]));
                    acc[hh][q][3] = FADD(acc[hh][q][3], FMUL(xv[7], w[7][q]));
                }
            }
        }

        if (ch < 7) {   // write next chunk into the other buffer
            *(float4*)&Xs[cur ^ 1][srow * XS6_STRIDE + sseg * 8]     = nx0;
            *(float4*)&Xs[cur ^ 1][srow * XS6_STRIDE + sseg * 8 + 4] = nx1;
        }
        __syncthreads();
    }

#pragma unroll
    for (int hh = 0; hh < 2; ++hh) {
        float* __restrict__ op = &feats32[((h0 + hh) * 32768 + row0 + lane) * 64 + k0];
        float4 o0, o1;
        o0.x = FADD(FADD(acc[hh][0][0], acc[hh][0][1]), FADD(acc[hh][0][2], acc[hh][0][3]));
        o0.y = FADD(FADD(acc[hh][1][0], acc[hh][1][1]), FADD(acc[hh][1][2], acc[hh][1][3]));
        o0.z = FADD(FADD(acc[hh][2][0], acc[hh][2][1]), FADD(acc[hh][2][2], acc[hh][2][3]));
        o0.w = FADD(FADD(acc[hh][3][0], acc[hh][3][1]), FADD(acc[hh][3][2], acc[hh][3][3]));
        o1.x = FADD(FADD(acc[hh][4][0], acc[hh][4][1]), FADD(acc[hh][4][2], acc[hh][4][3]));
        o1.y = FADD(FADD(acc[hh][5][0], acc[hh][5][1]), FADD(acc[hh][5][2], acc[hh][5][3]));
        o1.z = FADD(FADD(acc[hh][6][0], acc[hh][6][1]), FADD(acc[hh][6][2], acc[hh][6][3]));
        o1.w = FADD(FADD(acc[hh][7][0], acc[hh][7][1]), FADD(acc[hh][7][2], acc[hh][7][3]));
        *(float4*)&op[0] = o0;
        *(float4*)&op[4] = o1;
    }
}

// ---------------------------------------------------------------- logits (np emu)
__device__ float sse_dot64(const float* __restrict__ x, const float* __restrict__ y) {
    float a0 = 0.f, a1 = 0.f, a2 = 0.f, a3 = 0.f;
    for (int i = 0; i < 64; i += 8) {
        a0 = FADD(a0, FMUL(x[i + 0], y[i + 0]));
        a1 = FADD(a1, FMUL(x[i + 1], y[i + 1]));
        a2 = FADD(a2, FMUL(x[i + 2], y[i + 2]));
        a3 = FADD(a3, FMUL(x[i + 3], y[i + 3]));
        a0 = FADD(a0, FMUL(x[i + 4], y[i + 4]));
        a1 = FADD(a1, FMUL(x[i + 5], y[i + 5]));
        a2 = FADD(a2, FMUL(x[i + 6], y[i + 6]));
        a3 = FADD(a3, FMUL(x[i + 7], y[i + 7]));
    }
    return FADD(FADD(a0, a1), FADD(a2, a3));
}

__global__ __launch_bounds__(256) void logits_emu(const float* __restrict__ feats32,
                                                  const float* __restrict__ attn_s,
                                                  const float* __restrict__ attn_n,
                                                  float* __restrict__ a_s32,
                                                  float* __restrict__ a_n32) {
    int t = blockIdx.x * 256 + threadIdx.x;      // 262,144
    int row = t & 32767, h = t >> 15;
    const float* fr = &feats32[(h * 32768 + row) * 64];
    a_s32[h * 32768 + row] = sse_dot64(fr, &attn_s[h * 64]);
    a_n32[h * 32768 + row] = sse_dot64(fr, &attn_n[h * 64]);
}

// ---------------------------------------------------------------- attention (np-fp32 emu, v2)
#define VT_STRIDE 264
__global__ __launch_bounds__(256) void attn_emu(const float* __restrict__ A,
                                                const unsigned short* __restrict__ feats_bf,
                                                const float* __restrict__ a_s32,
                                                const float* __restrict__ a_n32,
                                                const float* __restrict__ biases,
                                                float* __restrict__ out0,
                                                float* __restrict__ view32) {
    __shared__ alignas(16) unsigned short Vt[64 * VT_STRIDE];   // 33792 B
    __shared__ alignas(16) unsigned int   Abits[64][8];         //  2048 B
    __shared__ alignas(16) float an_l[8][256];                  //  8192 B
    __shared__ alignas(16) float as_l[8][64];                   //  2048 B  = 46080 B

    const int tid = threadIdx.x;
    const int b = blockIdx.x >> 2;
    const int row0 = (blockIdx.x & 3) * 64;
    const int w = tid >> 6, lane = tid & 63;
    const int m = lane & 15, jq = lane >> 4;

    // stage adjacency as bitmask: 64 rows x 256 bits
    {
        int i = tid >> 2, sg = tid & 3;
        const float* ar = &A[(((b << 8) + row0 + i) << 8) + sg * 64];
        unsigned int w0 = 0, w1 = 0;
#pragma unroll
        for (int q = 0; q < 8; ++q) {
            float4 av = *(const float4*)&ar[q * 4];
            unsigned int m4 = (av.x != 0.f ? 1u : 0u) | (av.y != 0.f ? 2u : 0u) |
                              (av.z != 0.f ? 4u : 0u) | (av.w != 0.f ? 8u : 0u);
            w0 |= m4 << (q * 4);
        }
#pragma unroll
        for (int q = 8; q < 16; ++q) {
            float4 av = *(const float4*)&ar[q * 4];
            unsigned int m4 = (av.x != 0.f ? 1u : 0u) | (av.y != 0.f ? 2u : 0u) |
                              (av.z != 0.f ? 4u : 0u) | (av.w != 0.f ? 8u : 0u);
            w1 |= m4 << ((q - 8) * 4);
        }
        Abits[i][sg * 2]     = w0;
        Abits[i][sg * 2 + 1] = w1;
    }
    // stage logits (all heads)
    for (int idx = tid; idx < 2048; idx += 256) {
        int h = idx >> 8, j = idx & 255;
        an_l[h][j] = a_n32[h * 32768 + (b << 8) + j];
    }
    for (int idx = tid; idx < 512; idx += 256) {
        int h = idx >> 6, i = idx & 63;
        as_l[h][i] = a_s32[h * 32768 + (b << 8) + row0 + i];
    }
    __syncthreads();

    const int i_ln = w * 16 + m;
    const int myrow = row0 + i_ln;
    unsigned int abits[8];
#pragma unroll
    for (int u = 0; u < 8; ++u) abits[u] = Abits[i_ln][u];

    float view_acc[8][8] = {};

    for (int h = 0; h < 8; ++h) {
        __syncthreads();
        {   // stage V^T for this head: 16B global loads, scalar LDS writes
            int jb = w;
#pragma unroll
            for (int it = 0; it < 8; ++it) {
                int j  = jb * 64 + it * 8 + (lane >> 3);
                int kg = lane & 7;
                s16x8 v8 = *(const s16x8*)&feats_bf[(((b << 8) + j) << 9) + (h << 6) + kg * 8];
#pragma unroll
                for (int u = 0; u < 8; ++u)
                    Vt[(kg * 8 + u) * VT_STRIDE + j] = (unsigned short)v8[u];
            }
        }
        __syncthreads();

        const float asv = as_l[h][i_ln];

        // ---- logits once, tracking local max
        float ev[8][8];
        float Mloc = -3.4e38f;
#pragma unroll
        for (int kb = 0; kb < 8; ++kb) {
            int jbase = kb * 32 + jq * 8;
            float4 an0 = *(const float4*)&an_l[h][jbase];
            float4 an1 = *(const float4*)&an_l[h][jbase + 4];
            float anv[8] = { an0.x, an0.y, an0.z, an0.w, an1.x, an1.y, an1.z, an1.w };
            unsigned int mb = (abits[kb] >> (jq * 8)) & 0xffu;
#pragma unroll
            for (int t = 0; t < 8; ++t) {
                float lg = FADD(asv, anv[t]);
                float lr = lg > 0.f ? lg : FMUL(0.2f, lg);
                float v  = (mb & (1u << t)) ? lr : FADD(lr, MASKC);
                ev[kb][t] = v;
                Mloc = fmaxf(Mloc, v);
            }
        }
        // ---- M: order-free cross-lane max over the row's 4 lanes
        Mloc = fmaxf(Mloc, __shfl_xor(Mloc, 16, 64));
        Mloc = fmaxf(Mloc, __shfl_xor(Mloc, 32, 64));
        const float Mi = Mloc;

        // ---- exp ONCE
#pragma unroll
        for (int kb = 0; kb < 8; ++kb)
#pragma unroll
            for (int t = 0; t < 8; ++t)
                ev[kb][t] = expf_cr(FSUB(ev[kb][t], Mi));

        // ---- S: numpy pairwise tree via shuffles (exact; FADD commutative)
        float blkS[2];
#pragma unroll
        for (int blk = 0; blk < 2; ++blk) {
            float d[8];
#pragma unroll
            for (int t = 0; t < 8; ++t) {
                float s0 = FADD(ev[blk * 4 + 0][t], __shfl_xor(ev[blk * 4 + 0][t], 32, 64));
                float s1 = FADD(ev[blk * 4 + 1][t], __shfl_xor(ev[blk * 4 + 1][t], 32, 64));
                float s2 = FADD(ev[blk * 4 + 2][t], __shfl_xor(ev[blk * 4 + 2][t], 32, 64));
                float s3 = FADD(ev[blk * 4 + 3][t], __shfl_xor(ev[blk * 4 + 3][t], 32, 64));
                float cc = FADD(FADD(s0, s1), FADD(s2, s3));   // c[l]
                d[t] = FADD(cc, __shfl_xor(cc, 16, 64));       // d[l] = c[l]+c[l+8]
            }
            float e4[4], f2[2];
#pragma unroll
            for (int t = 0; t < 4; ++t) e4[t] = FADD(d[t], d[t + 4]);
            f2[0] = FADD(e4[0], e4[2]);
            f2[1] = FADD(e4[1], e4[3]);
            blkS[blk] = FADD(f2[0], f2[1]);
        }
        const float Si = FADD(blkS[0], blkS[1]);

        // ---- p, view accumulate, PV MFMA
        s16x8 pfrag[8];
#pragma unroll
        for (int kb = 0; kb < 8; ++kb) {
            s16x8 pf;
#pragma unroll
            for (int t = 0; t < 8; ++t) {
                float p = FDIV(ev[kb][t], Si);
                view_acc[kb][t] = FADD(view_acc[kb][t], FMUL(p, 0.125f));
                pf[t] = (short)f2bf(p);
            }
            pfrag[kb] = pf;
        }

        fx4 acc[4] = {};
#pragma unroll
        for (int kb = 0; kb < 8; ++kb) {
            int jo = kb * 32 + jq * 8;
#pragma unroll
            for (int nf = 0; nf < 4; ++nf) {
                s16x8 vf = *(const s16x8*)&Vt[(nf * 16 + m) * VT_STRIDE + jo];
                acc[nf] = mfma_bf16_16x16x32(pfrag[kb], vf, acc[nf]);
            }
        }
#pragma unroll
        for (int nf = 0; nf < 4; ++nf) {
            float bias = biases[h * 64 + nf * 16 + m];
#pragma unroll
            for (int r = 0; r < 4; ++r) {
                float val = acc[nf][r] + bias;
                val = val > 0.f ? val : 0.f;
                int gi = (b << 8) + row0 + w * 16 + jq * 4 + r;
                out0[gi * 512 + h * 64 + nf * 16 + m] = val;
            }
        }
    }

#pragma unroll
    for (int kb = 0; kb < 8; ++kb) {
        int base = (((b << 8) + myrow) << 8) + kb * 32 + jq * 8;
        float4 v0, v1;
        v0.x = view_acc[kb][0]; v0.y = view_acc[kb][1]; v0.z = view_acc[kb][2]; v0.w = view_acc[kb][3];
        v1.x = view_acc[kb][4]; v1.y = view_acc[kb][5]; v1.z = view_acc[kb][6]; v1.w = view_acc[kb][7];
        *(float4*)&view32[base]     = v0;
        *(float4*)&view32[base + 4] = v1;
    }
}

// ---------------------------------------------------------------- pool / temp / thresh
__global__ __launch_bounds__(256) void pool_emu(const float* __restrict__ view32,
                                                float* __restrict__ pooled) {
    int t = blockIdx.x * 256 + threadIdx.x;      // 2,097,152
    int j = t & 127, i = (t >> 7) & 127, b = t >> 14;
    const float* p = &view32[(b << 16) + (2 * i) * 256 + 2 * j];
    pooled[t] = fmaxf(fmaxf(p[0], p[1]), fmaxf(p[256], p[257]));
}

// temp[b,i,k] = SSE dot over j=0..127: pooled row (wave-broadcast) x alpha[:,k]
// (k per lane -> alpha[j*128+k] contiguous ACROSS LANES = coalesced).
__global__ __launch_bounds__(256) void temp_emu(const float* __restrict__ pooled,
                                                const float* __restrict__ alpha,
                                                float* __restrict__ temp) {
    int t = blockIdx.x * 256 + threadIdx.x;      // 2,097,152
    int k = t & 127, i = (t >> 7) & 127, b = t >> 14;
    const float* pr = &pooled[(b << 14) + i * 128];
    const float* ap = &alpha[k];                  // stride 128 per thread, coalesced per wave
    float a0 = 0.f, a1 = 0.f, a2 = 0.f, a3 = 0.f;
    for (int j = 0; j < 128; j += 8) {
        a0 = FADD(a0, FMUL(pr[j + 0], ap[(j + 0) * 128]));
        a1 = FADD(a1, FMUL(pr[j + 1], ap[(j + 1) * 128]));
        a2 = FADD(a2, FMUL(pr[j + 2], ap[(j + 2) * 128]));
        a3 = FADD(a3, FMUL(pr[j + 3], ap[(j + 3) * 128]));
        a0 = FADD(a0, FMUL(pr[j + 4], ap[(j + 4) * 128]));
        a1 = FADD(a1, FMUL(pr[j + 5], ap[(j + 5) * 128]));
        a2 = FADD(a2, FMUL(pr[j + 6], ap[(j + 6) * 128]));
        a3 = FADD(a3, FMUL(pr[j + 7], ap[(j + 7) * 128]));
    }
    temp[t] = FADD(FADD(a0, a1), FADD(a2, a3));
}

// s[b] = numpy pairwise over 16384 (128 leaves of pw128, balanced binary tree)
__global__ __launch_bounds__(128) void thresh_emu(const float* __restrict__ temp,
                                                  float* __restrict__ thresh32) {
    __shared__ float red[128];
    int l = threadIdx.x, b = blockIdx.x;
    red[l] = pw128(&temp[(b << 14) + l * 128]);
    __syncthreads();
    for (int s = 64; s >= 1; s >>= 1) {
        float v = 0.f;
        if (l < s) v = FADD(red[2 * l], red[2 * l + 1]);
        __syncthreads();
        if (l < s) red[l] = v;
        __syncthreads();
    }
    if (l == 0) {
        float sfin = red[0];
        float e = expf_cr(-sfin);                 // np.exp(-s) fp32 (correctly rounded)
        thresh32[b] = FDIV(1.0f, FADD(1.0f, e)); // 1/(1+e)
    }
}

// ---------------------------------------------------------------- binarize (fp32)
__global__ __launch_bounds__(256) void binarize_emu(const float* __restrict__ view32,
                                                    const float* __restrict__ thresh32,
                                                    float* __restrict__ out1) {
    int g = blockIdx.x * 256 + threadIdx.x;
    int e = g * 4;
    int b = e >> 16, i = (e >> 8) & 255, j = e & 255;
    float th = thresh32[b];
    float4 v = *(const float4*)&view32[e];
    float4 o;
    o.x = (FADD(v.x, (i == j + 0) ? 1.f : 0.f) < th) ? 1.f : 0.f;
    o.y = (FADD(v.y, (i == j + 1) ? 1.f : 0.f) < th) ? 1.f : 0.f;
    o.z = (FADD(v.z, (i == j + 2) ? 1.f : 0.f) < th) ? 1.f : 0.f;
    o.w = (FADD(v.w, (i == j + 3) ? 1.f : 0.f) < th) ? 1.f : 0.f;
    *(float4*)&out1[e] = o;
}

// ---------------------------------------------------------------- launch
static inline void ck_launch(const char* name) {
    hipError_t e = hipGetLastError();
    if (e != hipSuccess)
        fprintf(stderr, "[gat] %s launch error %d: %s\n", name, (int)e, hipGetErrorString(e));
}

extern "C" void kernel_launch(void* const* d_in, const int* in_sizes, int n_in,
                              void* d_out, int out_size, void* d_ws, size_t ws_size,
                              hipStream_t stream) {
    const float* X      = (const float*)d_in[0];
    const float* A      = (const float*)d_in[1];
    const float* kern   = (const float*)d_in[2];
    const float* biases = (const float*)d_in[3];
    const float* attn_s = (const float*)d_in[4];
    const float* attn_n = (const float*)d_in[5];
    const float* alpha  = (const float*)d_in[6];

    char* ws = (char*)d_ws;
    unsigned short* feats_bf = (unsigned short*)(ws);             //  33,554,432 B
    float*          feats32  = (float*)(ws + 33554432);           //  67,108,864 B
    float*          view32   = (float*)(ws + 100663296);          //  33,554,432 B
    float*          a_s32    = (float*)(ws + 134217728);          //   1,048,576 B
    float*          a_n32    = (float*)(ws + 135266304);          //   1,048,576 B
    float*          pooled   = (float*)(ws + 136314880);          //   8,388,608 B
    float*          temp     = (float*)(ws + 144703488);          //   8,388,608 B
    float*          thresh32 = (float*)(ws + 153092096);          //         512 B
    unsigned short* wkt      = (unsigned short*)(ws + 153092608); //     524,288 B

    // kern_r (8 MB) aliased onto view32's region: dead until attn_emu writes
    // view32, and feats32_emu6 (the only reader) runs strictly before that.
    float*          kern_r   = (float*)(ws + 100663296);

    float* out0 = (float*)d_out;
    float* out1 = out0 + 16777216;

    repack_w    <<<1024, 256, 0, stream>>>(kern, wkt);              ck_launch("repack_w");
    repack_k32  <<<1024, 256, 0, stream>>>(kern, kern_r);           ck_launch("repack_k32");
    gemm_feats  <<<1024, 256, 0, stream>>>(X, wkt, feats_bf);       ck_launch("gemm_feats");
    feats32_emu6<<<2048, 512, 0, stream>>>(X, kern_r, feats32);     ck_launch("feats32_emu6");
    logits_emu  <<<1024, 256, 0, stream>>>(feats32, attn_s, attn_n, a_s32, a_n32);
                                                                    ck_launch("logits_emu");
    attn_emu    <<<512, 256, 0, stream>>>(A, feats_bf, a_s32, a_n32, biases, out0, view32);
                                                                    ck_launch("attn_emu");
    pool_emu    <<<8192, 256, 0, stream>>>(view32, pooled);         ck_launch("pool_emu");
    temp_emu    <<<8192, 256, 0, stream>>>(pooled, alpha, temp);    ck_launch("temp_emu");
    thresh_emu  <<<128, 128, 0, stream>>>(temp, thresh32);          ck_launch("thresh_emu");
    binarize_emu<<<8192, 256, 0, stream>>>(view32, thresh32, out1); ck_launch("binarize_emu");
}

// Round 9
// 625.942 us; speedup vs baseline: 2.9984x; 1.0897x over previous
//
#include <hip/hip_runtime.h>
#include <hip/hip_bf16.h>
#include <cstdio>
#include <math.h>

// GraphAttention forward, MI355X/gfx950.  Inputs/outputs FLOAT32.
// out0: bf16 MFMA path (PASSES at 2e-2).
// out1: EXACT numpy-fp32 emulation (established R4-R6: fp64 is not enough; the
// binary threshold decisions require bit-identical fp32):
//   - einsum sums (feats over f, logits over k, temp over j): SSE 4-lane 1-acc
//     dot, lane = idx%4, hsum ((a0+a1)+(a2+a3))
//   - np.sum reductions: numpy pairwise_sum, AVX512 base case
//   - exp/sigmoid: correctly-rounded fp32 via fp64 exp
//   - all fp32 ops via __f*_rn (no FMA contraction)
//
// R14 (resubmitted R15 — previous run failed on container acquire, not kernel):
// the same 1.7e10-MAC projection GEMM was computed TWICE — bf16 MFMA
// (gemm_feats, feeding out0/PV) and exact np-fp32 (feats32_emu6). out0 only
// needs feats_bf at 2e-2, and f2bf(exact fp32) is strictly MORE accurate than
// the bf16-input MFMA result. gemm_feats + repack_w deleted; feats_bf now
// produced by a trivial convert kernel from feats32 (~100MB, memory-bound).
// out1 path untouched.

typedef __attribute__((ext_vector_type(8))) short   s16x8;
typedef __attribute__((ext_vector_type(8))) __bf16  bf16x8;
typedef __attribute__((ext_vector_type(4))) float   fx4;

#define FADD __fadd_rn
#define FMUL __fmul_rn
#define FSUB __fsub_rn
#define FDIV __fdiv_rn
#define MASKC (-9999998976.0f)   // fl32(-1e10)

__device__ __forceinline__ fx4 mfma_bf16_16x16x32(s16x8 a, s16x8 b, fx4 c) {
    return __builtin_amdgcn_mfma_f32_16x16x32_bf16(
        __builtin_bit_cast(bf16x8, a), __builtin_bit_cast(bf16x8, b), c, 0, 0, 0);
}
__device__ __forceinline__ unsigned short f2bf(float f) {
    unsigned int x = __builtin_bit_cast(unsigned int, f);
    unsigned int lsb = (x >> 16) & 1u;
    x += 0x7fffu + lsb;
    return (unsigned short)(x >> 16);
}
__device__ __forceinline__ float expf_cr(float x) {   // correctly-rounded expf
    return (float)exp((double)x);
}

// numpy pairwise_sum base (n=128), AVX512 flavor.
__device__ float pw128(const float* a) {
    float c[16];
#pragma unroll
    for (int l = 0; l < 16; ++l) {
        float t0 = FADD(FADD(a[l], a[16 + l]), FADD(a[32 + l], a[48 + l]));
        float t1 = FADD(FADD(a[64 + l], a[80 + l]), FADD(a[96 + l], a[112 + l]));
        c[l] = FADD(t0, t1);
    }
    float d[8], e[4], f[2];
#pragma unroll
    for (int l = 0; l < 8; ++l) d[l] = FADD(c[l], c[l + 8]);
#pragma unroll
    for (int l = 0; l < 4; ++l) e[l] = FADD(d[l], d[l + 4]);
#pragma unroll
    for (int l = 0; l < 2; ++l) f[l] = FADD(e[l], e[l + 2]);
    return FADD(f[0], f[1]);
}

// ---------------------------------------------------------------- repacks
// fp32 repack for feats32: kern_r[((h*8+kg)*512+f)*8 + kk]
__global__ __launch_bounds__(256) void repack_k32(const float* __restrict__ kern,
                                                  float* __restrict__ kern_r) {
    int t = blockIdx.x * 256 + threadIdx.x;      // 262,144
    int kk = t & 7, f = (t >> 3) & 511, kgh = t >> 12;
    int kg = kgh & 7, h = kgh >> 3;
    kern_r[t] = kern[(h * 512 + f) * 64 + kg * 8 + kk];
}

// ---------------------------------------------------------------- feats32 (np emu, v6)
// emu4's proven weight path + X LDS double-buffer (FCH=64, one barrier/chunk).
#define FCH6 64
#define XS6_STRIDE 68   // floats; 16B-aligned
__global__ __launch_bounds__(512) void feats32_emu6(const float* __restrict__ X,
                                                    const float* __restrict__ kern_r,
                                                    float* __restrict__ feats32) {
    __shared__ alignas(16) float Xs[2][64 * XS6_STRIDE];   // 34,816 B
    const int tid = threadIdx.x;
    const int hg = blockIdx.x >> 9;          // 0..3  (grid = 4 * 512)
    const int rb = blockIdx.x & 511;         // 0..511
    const int h0 = hg * 2;
    const int lane = tid & 63;
    const int kg = __builtin_amdgcn_readfirstlane(tid >> 6);   // wave-uniform 0..7
    const int k0 = kg * 8;
    const int row0 = rb * 64;
    const int srow = tid >> 3, sseg = tid & 7;   // staging: 64 rows x 8 segs x 8 floats

    float acc[2][8][4];
#pragma unroll
    for (int hh = 0; hh < 2; ++hh)
#pragma unroll
        for (int q = 0; q < 8; ++q)
#pragma unroll
            for (int l = 0; l < 4; ++l) acc[hh][q][l] = 0.f;

    // per-(h,kg) weight slices, 16KB each, contiguous
    const float* __restrict__ kp0 = &kern_r[(((h0 + 0) * 8 + kg) * 512) * 8];
    const float* __restrict__ kp1 = &kern_r[(((h0 + 1) * 8 + kg) * 512) * 8];

    // prologue: stage chunk 0
    {
        const float* gp = &X[(row0 + srow) * 512 + sseg * 8];
        *(float4*)&Xs[0][srow * XS6_STRIDE + sseg * 8]     = *(const float4*)gp;
        *(float4*)&Xs[0][srow * XS6_STRIDE + sseg * 8 + 4] = *(const float4*)(gp + 4);
    }
    __syncthreads();

    for (int ch = 0; ch < 8; ++ch) {
        const int fc = ch * FCH6;
        const int cur = ch & 1;
        float4 nx0, nx1;
        if (ch < 7) {   // issue next-chunk global loads; land during compute
            const float* gp = &X[(row0 + srow) * 512 + fc + FCH6 + sseg * 8];
            nx0 = *(const float4*)gp;
            nx1 = *(const float4*)(gp + 4);
        }

        const float* __restrict__ xrow = &Xs[cur][lane * XS6_STRIDE];
        for (int fo = 0; fo < FCH6; fo += 8) {
            float xv[8];
            {
                float4 xa = *(const float4*)&xrow[fo];
                float4 xb = *(const float4*)&xrow[fo + 4];
                xv[0] = xa.x; xv[1] = xa.y; xv[2] = xa.z; xv[3] = xa.w;
                xv[4] = xb.x; xv[5] = xb.y; xv[6] = xb.z; xv[7] = xb.w;
            }
#pragma unroll
            for (int hh = 0; hh < 2; ++hh) {
                const float* __restrict__ kp = (hh == 0 ? kp0 : kp1) + (fc + fo) * 8;
                float w[8][8];   // w[j][q] = kern[h][fc+fo+j][k0+q]; 256B contiguous
#pragma unroll
                for (int j = 0; j < 8; ++j) {
                    float4 lo = *(const float4*)&kp[j * 8];
                    float4 hi = *(const float4*)&kp[j * 8 + 4];
                    w[j][0] = lo.x; w[j][1] = lo.y; w[j][2] = lo.z; w[j][3] = lo.w;
                    w[j][4] = hi.x; w[j][5] = hi.y; w[j][6] = hi.z; w[j][7] = hi.w;
                }
#pragma unroll
                for (int q = 0; q < 8; ++q) {
                    acc[hh][q][0] = FADD(acc[hh][q][0], FMUL(xv[0], w[0][q]));
                    acc[hh][q][1] = FADD(acc[hh][q][1], FMUL(xv[1], w[1][q]));
                    acc[hh][q][2] = FADD(acc[hh][q][2], FMUL(xv[2], w[2][q]));
                    acc[hh][q][3] = FADD(acc[hh][q][3], FMUL(xv[3], w[3][q]));
                    acc[hh][q][0] = FADD(acc[hh][q][0], FMUL(xv[4], w[4][q]));
                    acc[hh][q][1] = FADD(acc[hh][q][1], FMUL(xv[5], w[5][q]));
                    acc[hh][q][2] = FADD(acc[hh][q][2], FMUL(xv[6], w[6][q]));
                    acc[hh][q][3] = FADD(acc[hh][q][3], FMUL(xv[7], w[7][q]));
                }
            }
        }

        if (ch < 7) {   // write next chunk into the other buffer
            *(float4*)&Xs[cur ^ 1][srow * XS6_STRIDE + sseg * 8]     = nx0;
            *(float4*)&Xs[cur ^ 1][srow * XS6_STRIDE + sseg * 8 + 4] = nx1;
        }
        __syncthreads();
    }

#pragma unroll
    for (int hh = 0; hh < 2; ++hh) {
        float* __restrict__ op = &feats32[((h0 + hh) * 32768 + row0 + lane) * 64 + k0];
        float4 o0, o1;
        o0.x = FADD(FADD(acc[hh][0][0], acc[hh][0][1]), FADD(acc[hh][0][2], acc[hh][0][3]));
        o0.y = FADD(FADD(acc[hh][1][0], acc[hh][1][1]), FADD(acc[hh][1][2], acc[hh][1][3]));
        o0.z = FADD(FADD(acc[hh][2][0], acc[hh][2][1]), FADD(acc[hh][2][2], acc[hh][2][3]));
        o0.w = FADD(FADD(acc[hh][3][0], acc[hh][3][1]), FADD(acc[hh][3][2], acc[hh][3][3]));
        o1.x = FADD(FADD(acc[hh][4][0], acc[hh][4][1]), FADD(acc[hh][4][2], acc[hh][4][3]));
        o1.y = FADD(FADD(acc[hh][5][0], acc[hh][5][1]), FADD(acc[hh][5][2], acc[hh][5][3]));
        o1.z = FADD(FADD(acc[hh][6][0], acc[hh][6][1]), FADD(acc[hh][6][2], acc[hh][6][3]));
        o1.w = FADD(FADD(acc[hh][7][0], acc[hh][7][1]), FADD(acc[hh][7][2], acc[hh][7][3]));
        *(float4*)&op[0] = o0;
        *(float4*)&op[4] = o1;
    }
}

// ---------------------------------------------------------------- feats32 -> bf16
// feats_bf[row*512 + h*64 + k] = f2bf(feats32[(h*32768+row)*64 + k])
__global__ __launch_bounds__(256) void feats_to_bf(const float* __restrict__ feats32,
                                                   unsigned short* __restrict__ feats_bf) {
    int t = blockIdx.x * 256 + threadIdx.x;      // 4,194,304
    int e = t * 4;
    int k = e & 63, row = (e >> 6) & 32767, h = e >> 21;
    float4 v = *(const float4*)&feats32[e];
    ushort4 o;
    o.x = f2bf(v.x); o.y = f2bf(v.y); o.z = f2bf(v.z); o.w = f2bf(v.w);
    *(ushort4*)&feats_bf[(row << 9) + (h << 6) + k] = o;
}

// ---------------------------------------------------------------- logits (np emu)
__device__ float sse_dot64(const float* __restrict__ x, const float* __restrict__ y) {
    float a0 = 0.f, a1 = 0.f, a2 = 0.f, a3 = 0.f;
    for (int i = 0; i < 64; i += 8) {
        a0 = FADD(a0, FMUL(x[i + 0], y[i + 0]));
        a1 = FADD(a1, FMUL(x[i + 1], y[i + 1]));
        a2 = FADD(a2, FMUL(x[i + 2], y[i + 2]));
        a3 = FADD(a3, FMUL(x[i + 3], y[i + 3]));
        a0 = FADD(a0, FMUL(x[i + 4], y[i + 4]));
        a1 = FADD(a1, FMUL(x[i + 5], y[i + 5]));
        a2 = FADD(a2, FMUL(x[i + 6], y[i + 6]));
        a3 = FADD(a3, FMUL(x[i + 7], y[i + 7]));
    }
    return FADD(FADD(a0, a1), FADD(a2, a3));
}

__global__ __launch_bounds__(256) void logits_emu(const float* __restrict__ feats32,
                                                  const float* __restrict__ attn_s,
                                                  const float* __restrict__ attn_n,
                                                  float* __restrict__ a_s32,
                                                  float* __restrict__ a_n32) {
    int t = blockIdx.x * 256 + threadIdx.x;      // 262,144
    int row = t & 32767, h = t >> 15;
    const float* fr = &feats32[(h * 32768 + row) * 64];
    a_s32[h * 32768 + row] = sse_dot64(fr, &attn_s[h * 64]);
    a_n32[h * 32768 + row] = sse_dot64(fr, &attn_n[h * 64]);
}

// ---------------------------------------------------------------- attention (np-fp32 emu, v2)
#define VT_STRIDE 264
__global__ __launch_bounds__(256) void attn_emu(const float* __restrict__ A,
                                                const unsigned short* __restrict__ feats_bf,
                                                const float* __restrict__ a_s32,
                                                const float* __restrict__ a_n32,
                                                const float* __restrict__ biases,
                                                float* __restrict__ out0,
                                                float* __restrict__ view32) {
    __shared__ alignas(16) unsigned short Vt[64 * VT_STRIDE];   // 33792 B
    __shared__ alignas(16) unsigned int   Abits[64][8];         //  2048 B
    __shared__ alignas(16) float an_l[8][256];                  //  8192 B
    __shared__ alignas(16) float as_l[8][64];                   //  2048 B  = 46080 B

    const int tid = threadIdx.x;
    const int b = blockIdx.x >> 2;
    const int row0 = (blockIdx.x & 3) * 64;
    const int w = tid >> 6, lane = tid & 63;
    const int m = lane & 15, jq = lane >> 4;

    // stage adjacency as bitmask: 64 rows x 256 bits
    {
        int i = tid >> 2, sg = tid & 3;
        const float* ar = &A[(((b << 8) + row0 + i) << 8) + sg * 64];
        unsigned int w0 = 0, w1 = 0;
#pragma unroll
        for (int q = 0; q < 8; ++q) {
            float4 av = *(const float4*)&ar[q * 4];
            unsigned int m4 = (av.x != 0.f ? 1u : 0u) | (av.y != 0.f ? 2u : 0u) |
                              (av.z != 0.f ? 4u : 0u) | (av.w != 0.f ? 8u : 0u);
            w0 |= m4 << (q * 4);
        }
#pragma unroll
        for (int q = 8; q < 16; ++q) {
            float4 av = *(const float4*)&ar[q * 4];
            unsigned int m4 = (av.x != 0.f ? 1u : 0u) | (av.y != 0.f ? 2u : 0u) |
                              (av.z != 0.f ? 4u : 0u) | (av.w != 0.f ? 8u : 0u);
            w1 |= m4 << ((q - 8) * 4);
        }
        Abits[i][sg * 2]     = w0;
        Abits[i][sg * 2 + 1] = w1;
    }
    // stage logits (all heads)
    for (int idx = tid; idx < 2048; idx += 256) {
        int h = idx >> 8, j = idx & 255;
        an_l[h][j] = a_n32[h * 32768 + (b << 8) + j];
    }
    for (int idx = tid; idx < 512; idx += 256) {
        int h = idx >> 6, i = idx & 63;
        as_l[h][i] = a_s32[h * 32768 + (b << 8) + row0 + i];
    }
    __syncthreads();

    const int i_ln = w * 16 + m;
    const int myrow = row0 + i_ln;
    unsigned int abits[8];
#pragma unroll
    for (int u = 0; u < 8; ++u) abits[u] = Abits[i_ln][u];

    float view_acc[8][8] = {};

    for (int h = 0; h < 8; ++h) {
        __syncthreads();
        {   // stage V^T for this head: 16B global loads, scalar LDS writes
            int jb = w;
#pragma unroll
            for (int it = 0; it < 8; ++it) {
                int j  = jb * 64 + it * 8 + (lane >> 3);
                int kg = lane & 7;
                s16x8 v8 = *(const s16x8*)&feats_bf[(((b << 8) + j) << 9) + (h << 6) + kg * 8];
#pragma unroll
                for (int u = 0; u < 8; ++u)
                    Vt[(kg * 8 + u) * VT_STRIDE + j] = (unsigned short)v8[u];
            }
        }
        __syncthreads();

        const float asv = as_l[h][i_ln];

        // ---- logits once, tracking local max
        float ev[8][8];
        float Mloc = -3.4e38f;
#pragma unroll
        for (int kb = 0; kb < 8; ++kb) {
            int jbase = kb * 32 + jq * 8;
            float4 an0 = *(const float4*)&an_l[h][jbase];
            float4 an1 = *(const float4*)&an_l[h][jbase + 4];
            float anv[8] = { an0.x, an0.y, an0.z, an0.w, an1.x, an1.y, an1.z, an1.w };
            unsigned int mb = (abits[kb] >> (jq * 8)) & 0xffu;
#pragma unroll
            for (int t = 0; t < 8; ++t) {
                float lg = FADD(asv, anv[t]);
                float lr = lg > 0.f ? lg : FMUL(0.2f, lg);
                float v  = (mb & (1u << t)) ? lr : FADD(lr, MASKC);
                ev[kb][t] = v;
                Mloc = fmaxf(Mloc, v);
            }
        }
        // ---- M: order-free cross-lane max over the row's 4 lanes
        Mloc = fmaxf(Mloc, __shfl_xor(Mloc, 16, 64));
        Mloc = fmaxf(Mloc, __shfl_xor(Mloc, 32, 64));
        const float Mi = Mloc;

        // ---- exp ONCE
#pragma unroll
        for (int kb = 0; kb < 8; ++kb)
#pragma unroll
            for (int t = 0; t < 8; ++t)
                ev[kb][t] = expf_cr(FSUB(ev[kb][t], Mi));

        // ---- S: numpy pairwise tree via shuffles (exact; FADD commutative)
        float blkS[2];
#pragma unroll
        for (int blk = 0; blk < 2; ++blk) {
            float d[8];
#pragma unroll
            for (int t = 0; t < 8; ++t) {
                float s0 = FADD(ev[blk * 4 + 0][t], __shfl_xor(ev[blk * 4 + 0][t], 32, 64));
                float s1 = FADD(ev[blk * 4 + 1][t], __shfl_xor(ev[blk * 4 + 1][t], 32, 64));
                float s2 = FADD(ev[blk * 4 + 2][t], __shfl_xor(ev[blk * 4 + 2][t], 32, 64));
                float s3 = FADD(ev[blk * 4 + 3][t], __shfl_xor(ev[blk * 4 + 3][t], 32, 64));
                float cc = FADD(FADD(s0, s1), FADD(s2, s3));   // c[l]
                d[t] = FADD(cc, __shfl_xor(cc, 16, 64));       // d[l] = c[l]+c[l+8]
            }
            float e4[4], f2[2];
#pragma unroll
            for (int t = 0; t < 4; ++t) e4[t] = FADD(d[t], d[t + 4]);
            f2[0] = FADD(e4[0], e4[2]);
            f2[1] = FADD(e4[1], e4[3]);
            blkS[blk] = FADD(f2[0], f2[1]);
        }
        const float Si = FADD(blkS[0], blkS[1]);

        // ---- p, view accumulate, PV MFMA
        s16x8 pfrag[8];
#pragma unroll
        for (int kb = 0; kb < 8; ++kb) {
            s16x8 pf;
#pragma unroll
            for (int t = 0; t < 8; ++t) {
                float p = FDIV(ev[kb][t], Si);
                view_acc[kb][t] = FADD(view_acc[kb][t], FMUL(p, 0.125f));
                pf[t] = (short)f2bf(p);
            }
            pfrag[kb] = pf;
        }

        fx4 acc[4] = {};
#pragma unroll
        for (int kb = 0; kb < 8; ++kb) {
            int jo = kb * 32 + jq * 8;
#pragma unroll
            for (int nf = 0; nf < 4; ++nf) {
                s16x8 vf = *(const s16x8*)&Vt[(nf * 16 + m) * VT_STRIDE + jo];
                acc[nf] = mfma_bf16_16x16x32(pfrag[kb], vf, acc[nf]);
            }
        }
#pragma unroll
        for (int nf = 0; nf < 4; ++nf) {
            float bias = biases[h * 64 + nf * 16 + m];
#pragma unroll
            for (int r = 0; r < 4; ++r) {
                float val = acc[nf][r] + bias;
                val = val > 0.f ? val : 0.f;
                int gi = (b << 8) + row0 + w * 16 + jq * 4 + r;
                out0[gi * 512 + h * 64 + nf * 16 + m] = val;
            }
        }
    }

#pragma unroll
    for (int kb = 0; kb < 8; ++kb) {
        int base = (((b << 8) + myrow) << 8) + kb * 32 + jq * 8;
        float4 v0, v1;
        v0.x = view_acc[kb][0]; v0.y = view_acc[kb][1]; v0.z = view_acc[kb][2]; v0.w = view_acc[kb][3];
        v1.x = view_acc[kb][4]; v1.y = view_acc[kb][5]; v1.z = view_acc[kb][6]; v1.w = view_acc[kb][7];
        *(float4*)&view32[base]     = v0;
        *(float4*)&view32[base + 4] = v1;
    }
}

// ---------------------------------------------------------------- pool / temp / thresh
__global__ __launch_bounds__(256) void pool_emu(const float* __restrict__ view32,
                                                float* __restrict__ pooled) {
    int t = blockIdx.x * 256 + threadIdx.x;      // 2,097,152
    int j = t & 127, i = (t >> 7) & 127, b = t >> 14;
    const float* p = &view32[(b << 16) + (2 * i) * 256 + 2 * j];
    pooled[t] = fmaxf(fmaxf(p[0], p[1]), fmaxf(p[256], p[257]));
}

// temp[b,i,k] = SSE dot over j=0..127: pooled row (wave-broadcast) x alpha[:,k]
// (k per lane -> alpha[j*128+k] contiguous ACROSS LANES = coalesced).
__global__ __launch_bounds__(256) void temp_emu(const float* __restrict__ pooled,
                                                const float* __restrict__ alpha,
                                                float* __restrict__ temp) {
    int t = blockIdx.x * 256 + threadIdx.x;      // 2,097,152
    int k = t & 127, i = (t >> 7) & 127, b = t >> 14;
    const float* pr = &pooled[(b << 14) + i * 128];
    const float* ap = &alpha[k];                  // stride 128 per thread, coalesced per wave
    float a0 = 0.f, a1 = 0.f, a2 = 0.f, a3 = 0.f;
    for (int j = 0; j < 128; j += 8) {
        a0 = FADD(a0, FMUL(pr[j + 0], ap[(j + 0) * 128]));
        a1 = FADD(a1, FMUL(pr[j + 1], ap[(j + 1) * 128]));
        a2 = FADD(a2, FMUL(pr[j + 2], ap[(j + 2) * 128]));
        a3 = FADD(a3, FMUL(pr[j + 3], ap[(j + 3) * 128]));
        a0 = FADD(a0, FMUL(pr[j + 4], ap[(j + 4) * 128]));
        a1 = FADD(a1, FMUL(pr[j + 5], ap[(j + 5) * 128]));
        a2 = FADD(a2, FMUL(pr[j + 6], ap[(j + 6) * 128]));
        a3 = FADD(a3, FMUL(pr[j + 7], ap[(j + 7) * 128]));
    }
    temp[t] = FADD(FADD(a0, a1), FADD(a2, a3));
}

// s[b] = numpy pairwise over 16384 (128 leaves of pw128, balanced binary tree)
__global__ __launch_bounds__(128) void thresh_emu(const float* __restrict__ temp,
                                                  float* __restrict__ thresh32) {
    __shared__ float red[128];
    int l = threadIdx.x, b = blockIdx.x;
    red[l] = pw128(&temp[(b << 14) + l * 128]);
    __syncthreads();
    for (int s = 64; s >= 1; s >>= 1) {
        float v = 0.f;
        if (l < s) v = FADD(red[2 * l], red[2 * l + 1]);
        __syncthreads();
        if (l < s) red[l] = v;
        __syncthreads();
    }
    if (l == 0) {
        float sfin = red[0];
        float e = expf_cr(-sfin);                 // np.exp(-s) fp32 (correctly rounded)
        thresh32[b] = FDIV(1.0f, FADD(1.0f, e)); // 1/(1+e)
    }
}

// ---------------------------------------------------------------- binarize (fp32)
__global__ __launch_bounds__(256) void binarize_emu(const float* __restrict__ view32,
                                                    const float* __restrict__ thresh32,
                                                    float* __restrict__ out1) {
    int g = blockIdx.x * 256 + threadIdx.x;
    int e = g * 4;
    int b = e >> 16, i = (e >> 8) & 255, j = e & 255;
    float th = thresh32[b];
    float4 v = *(const float4*)&view32[e];
    float4 o;
    o.x = (FADD(v.x, (i == j + 0) ? 1.f : 0.f) < th) ? 1.f : 0.f;
    o.y = (FADD(v.y, (i == j + 1) ? 1.f : 0.f) < th) ? 1.f : 0.f;
    o.z = (FADD(v.z, (i == j + 2) ? 1.f : 0.f) < th) ? 1.f : 0.f;
    o.w = (FADD(v.w, (i == j + 3) ? 1.f : 0.f) < th) ? 1.f : 0.f;
    *(float4*)&out1[e] = o;
}

// ---------------------------------------------------------------- launch
static inline void ck_launch(const char* name) {
    hipError_t e = hipGetLastError();
    if (e != hipSuccess)
        fprintf(stderr, "[gat] %s launch error %d: %s\n", name, (int)e, hipGetErrorString(e));
}

extern "C" void kernel_launch(void* const* d_in, const int* in_sizes, int n_in,
                              void* d_out, int out_size, void* d_ws, size_t ws_size,
                              hipStream_t stream) {
    const float* X      = (const float*)d_in[0];
    const float* A      = (const float*)d_in[1];
    const float* kern   = (const float*)d_in[2];
    const float* biases = (const float*)d_in[3];
    const float* attn_s = (const float*)d_in[4];
    const float* attn_n = (const float*)d_in[5];
    const float* alpha  = (const float*)d_in[6];

    char* ws = (char*)d_ws;
    unsigned short* feats_bf = (unsigned short*)(ws);             //  33,554,432 B
    float*          feats32  = (float*)(ws + 33554432);           //  67,108,864 B
    float*          view32   = (float*)(ws + 100663296);          //  33,554,432 B
    float*          a_s32    = (float*)(ws + 134217728);          //   1,048,576 B
    float*          a_n32    = (float*)(ws + 135266304);          //   1,048,576 B
    float*          pooled   = (float*)(ws + 136314880);          //   8,388,608 B
    float*          temp     = (float*)(ws + 144703488);          //   8,388,608 B
    float*          thresh32 = (float*)(ws + 153092096);          //         512 B

    // kern_r (8 MB) aliased onto view32's region: dead until attn_emu writes
    // view32, and feats32_emu6 (the only reader) runs strictly before that.
    float*          kern_r   = (float*)(ws + 100663296);

    float* out0 = (float*)d_out;
    float* out1 = out0 + 16777216;

    repack_k32  <<<1024, 256, 0, stream>>>(kern, kern_r);           ck_launch("repack_k32");
    feats32_emu6<<<2048, 512, 0, stream>>>(X, kern_r, feats32);     ck_launch("feats32_emu6");
    feats_to_bf <<<16384, 256, 0, stream>>>(feats32, feats_bf);     ck_launch("feats_to_bf");
    logits_emu  <<<1024, 256, 0, stream>>>(feats32, attn_s, attn_n, a_s32, a_n32);
                                                                    ck_launch("logits_emu");
    attn_emu    <<<512, 256, 0, stream>>>(A, feats_bf, a_s32, a_n32, biases, out0, view32);
                                                                    ck_launch("attn_emu");
    pool_emu    <<<8192, 256, 0, stream>>>(view32, pooled);         ck_launch("pool_emu");
    temp_emu    <<<8192, 256, 0, stream>>>(pooled, alpha, temp);    ck_launch("temp_emu");
    thresh_emu  <<<128, 128, 0, stream>>>(temp, thresh32);          ck_launch("thresh_emu");
    binarize_emu<<<8192, 256, 0, stream>>>(view32, thresh32, out1); ck_launch("binarize_emu");
}